// Round 1
// 270.498 us; speedup vs baseline: 1.0275x; 1.0275x over previous
//
#include <hip/hip_runtime.h>
#include <hip/hip_bf16.h>

#define D_IN  128
#define D_HID 256
#define CBITS 9
#define CSIZE 512          // nodes per coarse bucket
#define EPB   8192         // edges per coarse_bin block
#define CCAP  10240        // entry capacity per coarse bucket (mean ~9630 + slack)
#define GT_CAP 4096        // LDS order-tile capacity for a 128-node gather tile

typedef __bf16 bf16x8 __attribute__((ext_vector_type(8)));
typedef float  f32x4  __attribute__((ext_vector_type(4)));
typedef float  f32x2  __attribute__((ext_vector_type(2)));

__device__ __forceinline__ unsigned short f2bf(float f) {
    unsigned u = __float_as_uint(f);
    u += 0x7FFFu + ((u >> 16) & 1u);   // RNE
    return (unsigned short)(u >> 16);
}
__device__ __forceinline__ uint2 pack4(float4 v) {
    unsigned lo = (unsigned)f2bf(v.x) | ((unsigned)f2bf(v.y) << 16);
    unsigned hi = (unsigned)f2bf(v.z) | ((unsigned)f2bf(v.w) << 16);
    return make_uint2(lo, hi);
}
// pack 4 floats -> 4 fp8 e4m3 bytes (HW cvt)
__device__ __forceinline__ unsigned packfp8(float4 v) {
    int u = __builtin_amdgcn_cvt_pk_fp8_f32(v.x, v.y, 0, false);
    u = __builtin_amdgcn_cvt_pk_fp8_f32(v.z, v.w, u, true);
    return (unsigned)u;
}
// async 16B global -> LDS (vmcnt)
__device__ __forceinline__ void g2lds16(const void* g, void* l) {
    __builtin_amdgcn_global_load_lds(
        (const __attribute__((address_space(1))) unsigned int*)g,
        (__attribute__((address_space(3))) unsigned int*)l, 16, 0, 0);
}

// Fused prep: [0,NXB) convert x -> bf16+fp8; [NXB,NXB+32) pack B into MFMA-fragment
// order; last block zeros gcur + pooled_pad. One launch instead of four.
__global__ __launch_bounds__(256)
void prep(const float* __restrict__ x, unsigned short* __restrict__ xb,
          unsigned char* __restrict__ x8,
          const float* __restrict__ Wr2, const float* __restrict__ Wl2,
          unsigned short* __restrict__ Bsw,
          int* __restrict__ gcur, float* __restrict__ pooled_pad,
          long n16, int NXB, int NCB) {
    const int bid = blockIdx.x;
    const int tid = threadIdx.x;
    if (bid < NXB) {
        const long t = (long)bid * 256 + tid;
        if (t >= n16) return;
        const float4* x4 = (const float4*)x;
        float4 v0 = x4[t * 4], v1 = x4[t * 4 + 1], v2 = x4[t * 4 + 2], v3 = x4[t * 4 + 3];
        uint2 p0 = pack4(v0), p1 = pack4(v1), p2 = pack4(v2), p3 = pack4(v3);
        ((uint4*)xb)[t * 2]     = make_uint4(p0.x, p0.y, p1.x, p1.y);
        ((uint4*)xb)[t * 2 + 1] = make_uint4(p2.x, p2.y, p3.x, p3.y);
        ((uint4*)x8)[t] = make_uint4(packfp8(v0), packfp8(v1), packfp8(v2), packfp8(v3));
    } else if (bid < NXB + 32) {
        // Bsw[(((kk*4+wn2)*4+t)*64+lane)*8+e] = B[wn2*64+t*16+(lane&15)][kk*32+(lane>>4)*8+e]
        const int t_idx = (bid - NXB) * 256 + tid;
        const int lane = t_idx & 63;
        const int rest = t_idx >> 6;
        const int tt   = rest & 3;
        const int wn2  = (rest >> 2) & 3;
        const int kk   = rest >> 4;
        const int j = wn2 * 64 + tt * 16 + (lane & 15);
        const int k = kk * 32 + (lane >> 4) * 8;
        const float* src = (k < 128) ? &Wr2[j * 128 + k] : &Wl2[j * 128 + (k - 128)];
        float4 v0 = *(const float4*)src;
        float4 v1 = *(const float4*)(src + 4);
        uint2 p0 = pack4(v0), p1 = pack4(v1);
        *(uint4*)&Bsw[(long)t_idx * 8] = make_uint4(p0.x, p0.y, p1.x, p1.y);
    } else {
        for (int i = tid; i < NCB * 16; i += 256) gcur[i] = 0;
        for (int i = tid; i < 256 * 16; i += 256) pooled_pad[i] = 0.f;
    }
}

// Stage 1: coarse binning with 64B-exclusive writes (two-pass count/alloc/scatter).
// int64-vs-int32 edge dtype detected inline by wave 0 (hi dwords of first 64 entries).
__global__ __launch_bounds__(256)
void coarse_bin(const void* __restrict__ ei, int* __restrict__ gcur,
                unsigned* __restrict__ segc, int E, int NCB) {
    __shared__ int cnt[256];
    __shared__ int basel[256];
    __shared__ int s_is64;
    const int tid = threadIdx.x;
    const long e0 = (long)blockIdx.x * EPB;
    const int ecnt = (int)min((long)EPB, (long)E - e0);

    if (tid < 64) {
        const int v = ((const int*)ei)[2 * tid + 1];
        const unsigned long long b = __ballot(v != 0);
        if (tid == 0) s_is64 = (b == 0ull);
    }
    for (int i = tid; i < NCB; i += 256) cnt[i] = 0;
    __syncthreads();
    const int is64 = s_is64;

    for (int j = tid; j < ecnt; j += 256) {
        int t = is64 ? (int)((const long long*)ei)[E + e0 + j]
                     : ((const int*)ei)[E + e0 + j];
        atomicAdd(&cnt[t >> CBITS], 1);
    }
    __syncthreads();

    for (int c = tid; c < NCB; c += 256) {
        const int n = cnt[c];
        const int na = (n + 15) & ~15;
        int b = 0;
        if (na > 0) b = atomicAdd(&gcur[c * 16], na);
        basel[c] = b;
        cnt[c] = 0;
        unsigned* sp = segc + (long)c * CCAP;
        for (int i = n; i < na; ++i)
            if (b + i < CCAP) sp[b + i] = 0xFFFFFFFFu;
    }
    __syncthreads();

    for (int j = tid; j < ecnt; j += 256) {
        int s, t;
        if (is64) { const long long* p = (const long long*)ei; s = (int)p[e0 + j]; t = (int)p[E + e0 + j]; }
        else      { const int* p = (const int*)ei;             s = p[e0 + j];      t = p[E + e0 + j]; }
        const int c = t >> CBITS;
        const int r = atomicAdd(&cnt[c], 1);
        const int pos = basel[c] + r;
        if (pos < CCAP)
            segc[(long)c * CCAP + pos] = ((unsigned)s << CBITS) | (unsigned)(t & (CSIZE - 1));
    }
}

// Stage 2: per coarse bucket, histogram + scan + scatter -> dense node-ordered gorder.
__global__ __launch_bounds__(1024)
void refine(const int* __restrict__ gcur, const unsigned* __restrict__ segc,
            unsigned* __restrict__ gorder, int2* __restrict__ rowdeg, int M) {
    __shared__ unsigned order[CCAP];            // 40 KB
    __shared__ int degh[CSIZE], scn[CSIZE], cur[CSIZE];
    const int tid = threadIdx.x;
    const int cb = blockIdx.x;
    const int nbase = cb << CBITS;
    const int nn = min(CSIZE, M - nbase);
    const int len = min(gcur[cb * 16], CCAP);
    const unsigned* sp = segc + (long)cb * CCAP;

    if (tid < CSIZE) degh[tid] = 0;
    __syncthreads();
    for (int i = tid; i < len; i += 1024) {
        const unsigned e = sp[i];
        if (e != 0xFFFFFFFFu) atomicAdd(&degh[e & (CSIZE - 1)], 1);
    }
    __syncthreads();
    if (tid < CSIZE) scn[tid] = degh[tid];
    __syncthreads();
    for (int off = 1; off < CSIZE; off <<= 1) {
        int v = 0;
        if (tid >= off && tid < CSIZE) v = scn[tid - off];
        __syncthreads();
        if (tid < CSIZE) scn[tid] += v;
        __syncthreads();
    }
    if (tid < CSIZE) cur[tid] = scn[tid] - degh[tid];
    __syncthreads();
    for (int i = tid; i < len; i += 1024) {
        const unsigned e = sp[i];
        if (e != 0xFFFFFFFFu) {
            const int r = atomicAdd(&cur[e & (CSIZE - 1)], 1);
            order[r] = e >> CBITS;
        }
    }
    __syncthreads();
    const int total = scn[CSIZE - 1];
    unsigned* gp = gorder + (long)cb * CCAP;
    for (int i = tid; i < total; i += 1024) gp[i] = order[i];
    if (tid < nn)
        rowdeg[nbase + tid] = make_int2(cb * CCAP + (scn[tid] - degh[tid]), degh[tid]);
}

// Stage 3: per 128-node tile: stage order slice into LDS, fp8 register gather.
__global__ __launch_bounds__(1024)
void gather_tile(const unsigned char* __restrict__ x8, const unsigned* __restrict__ gorder,
                 const int2* __restrict__ rowdeg, unsigned short* __restrict__ aggb, int M) {
    __shared__ unsigned ordl[GT_CAP];           // 16 KB
    __shared__ int s_start, s_total;
    const int tid = threadIdx.x;
    const int first = blockIdx.x * 128;
    const int nn = min(128, M - first);

    if (tid == 0) {
        int2 r0 = rowdeg[first];
        int2 rl = rowdeg[first + nn - 1];
        s_start = r0.x;
        s_total = min(rl.x + rl.y - r0.x, GT_CAP);
    }
    __syncthreads();
    const int st = s_start, tot = s_total;
    for (int i = tid; i < tot; i += 1024) ordl[i] = gorder[st + i];
    __syncthreads();

    const int wave = tid >> 6;
    const int lane = tid & 63;
    const int sub = lane >> 5;
    const int c   = lane & 31;
    const unsigned* x32 = (const unsigned*)x8;   // row = 32 uints
    unsigned* ab32 = (unsigned*)aggb;            // row = 64 uints (bf16)

    for (int nl = wave; nl < nn; nl += 16) {
        const long node = (long)first + nl;
        const int2 rd = rowdeg[node];
        const int beg = rd.x - st;
        const int deg = min(rd.y, tot - beg);
        float a0 = 0.f, a1 = 0.f, a2 = 0.f, a3 = 0.f;
        int i = 0;
        for (; i + 8 <= deg; i += 8) {
            unsigned v0 = x32[(long)ordl[beg + i + sub]     * 32 + c];
            unsigned v1 = x32[(long)ordl[beg + i + 2 + sub] * 32 + c];
            unsigned v2 = x32[(long)ordl[beg + i + 4 + sub] * 32 + c];
            unsigned v3 = x32[(long)ordl[beg + i + 6 + sub] * 32 + c];
            f32x2 l0 = __builtin_amdgcn_cvt_pk_f32_fp8(v0, false);
            f32x2 h0 = __builtin_amdgcn_cvt_pk_f32_fp8(v0, true);
            f32x2 l1 = __builtin_amdgcn_cvt_pk_f32_fp8(v1, false);
            f32x2 h1 = __builtin_amdgcn_cvt_pk_f32_fp8(v1, true);
            f32x2 l2 = __builtin_amdgcn_cvt_pk_f32_fp8(v2, false);
            f32x2 h2 = __builtin_amdgcn_cvt_pk_f32_fp8(v2, true);
            f32x2 l3 = __builtin_amdgcn_cvt_pk_f32_fp8(v3, false);
            f32x2 h3 = __builtin_amdgcn_cvt_pk_f32_fp8(v3, true);
            a0 += l0.x + l1.x + l2.x + l3.x;
            a1 += l0.y + l1.y + l2.y + l3.y;
            a2 += h0.x + h1.x + h2.x + h3.x;
            a3 += h0.y + h1.y + h2.y + h3.y;
        }
        for (; i + 2 <= deg; i += 2) {
            unsigned v = x32[(long)ordl[beg + i + sub] * 32 + c];
            f32x2 lo = __builtin_amdgcn_cvt_pk_f32_fp8(v, false);
            f32x2 hi = __builtin_amdgcn_cvt_pk_f32_fp8(v, true);
            a0 += lo.x; a1 += lo.y; a2 += hi.x; a3 += hi.y;
        }
        if (i < deg && sub == 0) {
            unsigned v = x32[(long)ordl[beg + i] * 32 + c];
            f32x2 lo = __builtin_amdgcn_cvt_pk_f32_fp8(v, false);
            f32x2 hi = __builtin_amdgcn_cvt_pk_f32_fp8(v, true);
            a0 += lo.x; a1 += lo.y; a2 += hi.x; a3 += hi.y;
        }
        a0 += __shfl_xor(a0, 32);
        a1 += __shfl_xor(a1, 32);
        a2 += __shfl_xor(a2, 32);
        a3 += __shfl_xor(a3, 32);
        if (sub == 0) {
            const float rd2 = 1.0f / fmaxf((float)rd.y, 1.0f);
            unsigned w0 = (unsigned)f2bf(a0 * rd2) | ((unsigned)f2bf(a1 * rd2) << 16);
            unsigned w1 = (unsigned)f2bf(a2 * rd2) | ((unsigned)f2bf(a3 * rd2) << 16);
            *(uint2*)&ab32[node * 64 + c * 2] = make_uint2(w0, w1);
        }
    }
}

// LDS-staged GEMM v3: one block = 64 rows x 256 cols, 4 waves (each 64x64 output).
// Full-K A tile (64 x 256 bf16 = 32 KB, xb||aggb) staged via async
// global_load_lds width=16 -- 2048 outstanding 16B loads per block before a
// single vmcnt(0)+barrier (latency-bound fix: bulk MLP instead of 1-deep reg
// prefetch). Source chunks XOR-swizzled (cs = cl ^ (r&7)) so the linear LDS
// dest reads back conflict-free with ds_read_b128 (rule #21: swizzle source +
// read with same involution; 16-lane groups spread over all 8 bank-groups).
// B register double-buffered from L2-hot pre-swizzled Bsw. 33 KB LDS -> 4
// blocks/CU; stage/compute overlap comes from cross-block TLP.
__global__ __launch_bounds__(256, 4)
void gemm_pool(const unsigned short* __restrict__ xb, const unsigned short* __restrict__ aggb,
               const unsigned short* __restrict__ Bsw, const float* __restrict__ bias2,
               float* __restrict__ pooled_pad, int M) {
    __shared__ unsigned short As[64 * 256];   // 32 KB (64 rows x 32 swizzled 16B chunks)
    __shared__ float pool_l[256];
    const int tid  = threadIdx.x;
    const int lane = tid & 63;
    const int wn2  = tid >> 6;        // wave = 64-col group 0..3
    const int lrow = lane & 15;
    const int quad = lane >> 4;
    const long mbase = (long)blockIdx.x * 64;

    // ---- stage A rows into LDS (source-swizzled, dest linear) ----
    {
        const int cl = tid & 31;          // LDS chunk-in-row
        const int rw = tid >> 5;          // row mod 8 (constant across rounds)
        const int cs = cl ^ rw;           // source chunk feeding this LDS slot
        const unsigned short* base = (cs < 16) ? (xb + (long)cs * 8)
                                               : (aggb + (long)(cs - 16) * 8);
        #pragma unroll
        for (int s = 0; s < 8; ++s) {
            const long row = mbase + s * 8 + rw;
            g2lds16(base + row * 128, (char*)As + (s * 256 + tid) * 16);
        }
    }

    // ---- B frags for kk=0 (L2-hot) ----
    uint4 bC[4];
    #pragma unroll
    for (int t = 0; t < 4; ++t)
        bC[t] = *(const uint4*)&Bsw[(((long)wn2 * 4 + t) * 64 + lane) * 8];

    asm volatile("s_waitcnt vmcnt(0)" ::: "memory");
    __syncthreads();

    f32x4 acc[4][4] = {};
    #pragma unroll
    for (int kk = 0; kk < 8; ++kk) {
        uint4 bN[4];
        if (kk < 7) {
            #pragma unroll
            for (int t = 0; t < 4; ++t)
                bN[t] = *(const uint4*)&Bsw[((((long)(kk + 1) * 4 + wn2) * 4 + t) * 64 + lane) * 8];
        }
        uint4 aC[4];
        #pragma unroll
        for (int i = 0; i < 4; ++i) {
            const int r = i * 16 + lrow;  // r&7 == lrow&7
            aC[i] = *(const uint4*)((const char*)As +
                     r * 512 + (((kk * 4 + quad) ^ (lrow & 7)) * 16));
        }
        #pragma unroll
        for (int i = 0; i < 4; ++i)
            #pragma unroll
            for (int t = 0; t < 4; ++t)
                acc[i][t] = __builtin_amdgcn_mfma_f32_16x16x32_bf16(
                    *(bf16x8*)&aC[i], *(bf16x8*)&bC[t], acc[i][t], 0, 0, 0);
        if (kk < 7) {
            #pragma unroll
            for (int t = 0; t < 4; ++t) bC[t] = bN[t];
        }
    }

    // ---- bias + ReLU + row-masked column sums -> pooled ----
    #pragma unroll
    for (int t = 0; t < 4; ++t) {
        const int jl = wn2 * 64 + t * 16 + lrow;    // 0..255, unique per wave
        const float bv = bias2[jl];
        float s = 0.f;
        #pragma unroll
        for (int i = 0; i < 4; ++i) {
            const long rbase = mbase + i * 16 + quad * 4;
            #pragma unroll
            for (int r = 0; r < 4; ++r) {
                float h = fmaxf(acc[i][t][r] + bv, 0.f);
                if (rbase + r < M) s += h;
            }
        }
        s += __shfl_xor(s, 16);
        s += __shfl_xor(s, 32);
        if (quad == 0) pool_l[jl] = s;   // cols disjoint across waves: plain store
    }
    __syncthreads();
    atomicAdd(&pooled_pad[tid * 16], pool_l[tid]);
}

// pooled -> MLP head -> log_softmax. One block, 256 threads.
__global__ __launch_bounds__(256)
void head_kernel(const float* __restrict__ pooled_pad,
                 const float* __restrict__ W1, const float* __restrict__ b1,
                 const float* __restrict__ W2, const float* __restrict__ b2,
                 float* __restrict__ out, float invM) {
    __shared__ float pooled_s[256];
    __shared__ float z1_s[256];
    __shared__ float z2_s[10];
    const int j = threadIdx.x;

    pooled_s[j] = pooled_pad[j * 16] * invM;
    __syncthreads();

    const float4* w4 = (const float4*)(W1 + (long)j * 256);
    float sx = 0.f, sy = 0.f, sz = 0.f, sw = 0.f;
    #pragma unroll 8
    for (int k = 0; k < 64; ++k) {
        float4 w = w4[k];
        float4 p = *(const float4*)&pooled_s[k * 4];
        sx += w.x * p.x; sy += w.y * p.y; sz += w.z * p.z; sw += w.w * p.w;
    }
    z1_s[j] = fmaxf(b1[j] + sx + sy + sz + sw, 0.f);
    __syncthreads();

    if (j < 160) {
        const int c = j >> 4, q = j & 15;
        float s = 0.f;
        for (int k = q; k < 256; k += 16) s += W2[c * 256 + k] * z1_s[k];
        #pragma unroll
        for (int off = 8; off >= 1; off >>= 1) s += __shfl_down(s, off, 16);
        if (q == 0) z2_s[c] = s + b2[c];
    }
    __syncthreads();

    if (j == 0) {
        float mx = z2_s[0];
        for (int c = 1; c < 10; ++c) mx = fmaxf(mx, z2_s[c]);
        float se = 0.f;
        for (int c = 0; c < 10; ++c) se += expf(z2_s[c] - mx);
        const float ls = logf(se);
        for (int c = 0; c < 10; ++c) out[c] = z2_s[c] - mx - ls;
    }
}

extern "C" void kernel_launch(void* const* d_in, const int* in_sizes, int n_in,
                              void* d_out, int out_size, void* d_ws, size_t ws_size,
                              hipStream_t stream) {
    const float* x    = (const float*)d_in[0];
    const void*  ei   = d_in[1];
    const float* Wl   = (const float*)d_in[2];
    const float* Wr   = (const float*)d_in[3];
    const float* bias = (const float*)d_in[4];
    const float* W1   = (const float*)d_in[5];
    const float* b1   = (const float*)d_in[6];
    const float* W2   = (const float*)d_in[7];
    const float* b2   = (const float*)d_in[8];
    float* out = (float*)d_out;

    const int M = in_sizes[0] / D_IN;        // 100000 nodes
    const int E = in_sizes[1] / 2;           // 1.6M edges
    const int L = in_sizes[4] / D_HID;       // 3 layers
    const int NMB = (M + 127) / 128;         // 128-node tiles (782)
    const long Mpad = (long)NMB * 128;       // row-padded region size (GEMM OOB-safe)
    const int NCB = (M + CSIZE - 1) / CSIZE; // coarse buckets (196)
    const int NB1 = (E + EPB - 1) / EPB;     // coarse_bin blocks (196)
    const int NG  = (M + 63) / 64;           // gemm 64-row blocks (1563)

    // Only the LAST layer matters (h is overwritten each loop iteration).
    const float* Wl2   = Wl + (long)(L - 1) * D_HID * D_IN;
    const float* Wr2   = Wr + (long)(L - 1) * D_HID * D_IN;
    const float* bias2 = bias + (long)(L - 1) * D_HID;

    // workspace: xb[Mpad*128]bf16 | aggb[Mpad*128]bf16 | x8[Mpad*128]u8 | Bsw[256*256]bf16 |
    //            pooled_pad[256*16]f | gcur[NCB*16]i | segc[NCB*CCAP]u | gorder[NCB*CCAP]u |
    //            rowdeg[M]int2   (pad rows of xb/aggb are garbage; GEMM masks rows >= M)
    unsigned short* xb   = (unsigned short*)d_ws;
    unsigned short* aggb = xb + Mpad * D_IN;
    unsigned char*  x8   = (unsigned char*)(aggb + Mpad * D_IN);
    unsigned short* Bsw  = (unsigned short*)(x8 + Mpad * D_IN);
    float* pooled_pad    = (float*)(Bsw + 256 * 256);
    int*      gcur       = (int*)(pooled_pad + 256 * 16);
    unsigned* segc       = (unsigned*)(gcur + (long)NCB * 16);
    unsigned* gorder     = segc + (long)NCB * CCAP;
    int2*     rowdeg     = (int2*)(gorder + (long)NCB * CCAP);

    const long n16 = (long)M * 8;            // 16-float chunks of x
    const int NXB = (int)((n16 + 255) / 256);

    prep<<<NXB + 32 + 1, 256, 0, stream>>>(x, xb, x8, Wr2, Wl2, Bsw, gcur, pooled_pad,
                                           n16, NXB, NCB);
    coarse_bin<<<NB1, 256, 0, stream>>>(ei, gcur, segc, E, NCB);
    refine<<<NCB, 1024, 0, stream>>>(gcur, segc, gorder, rowdeg, M);
    gather_tile<<<NMB, 1024, 0, stream>>>(x8, gorder, rowdeg, aggb, M);

    gemm_pool<<<NG, 256, 0, stream>>>(xb, aggb, Bsw, bias2, pooled_pad, M);

    head_kernel<<<1, 256, 0, stream>>>(pooled_pad, W1, b1, W2, b2, out, 1.0f / (float)M);
}

// Round 2
// 240.351 us; speedup vs baseline: 1.1564x; 1.1254x over previous
//
#include <hip/hip_runtime.h>
#include <hip/hip_bf16.h>

#define D_IN  128
#define D_HID 256
#define CBITS 9
#define CSIZE 512          // nodes per coarse bucket
#define EPB   8192         // edges per coarse_bin block
#define CCAP  10240        // entry capacity per coarse bucket (mean ~9630 + slack)
#define GT_CAP 4096        // LDS order-tile capacity for a 128-node gather tile

typedef __bf16 bf16x8 __attribute__((ext_vector_type(8)));
typedef float  f32x4  __attribute__((ext_vector_type(4)));
typedef float  f32x2  __attribute__((ext_vector_type(2)));

__device__ __forceinline__ unsigned short f2bf(float f) {
    unsigned u = __float_as_uint(f);
    u += 0x7FFFu + ((u >> 16) & 1u);   // RNE
    return (unsigned short)(u >> 16);
}
__device__ __forceinline__ uint2 pack4(float4 v) {
    unsigned lo = (unsigned)f2bf(v.x) | ((unsigned)f2bf(v.y) << 16);
    unsigned hi = (unsigned)f2bf(v.z) | ((unsigned)f2bf(v.w) << 16);
    return make_uint2(lo, hi);
}
// pack 4 floats -> 4 fp8 e4m3 bytes (HW cvt)
__device__ __forceinline__ unsigned packfp8(float4 v) {
    int u = __builtin_amdgcn_cvt_pk_fp8_f32(v.x, v.y, 0, false);
    u = __builtin_amdgcn_cvt_pk_fp8_f32(v.z, v.w, u, true);
    return (unsigned)u;
}
// async 16B global -> LDS (vmcnt)
__device__ __forceinline__ void g2lds16(const void* g, void* l) {
    __builtin_amdgcn_global_load_lds(
        (const __attribute__((address_space(1))) unsigned int*)g,
        (__attribute__((address_space(3))) unsigned int*)l, 16, 0, 0);
}

// Fused prep: [0,NXB) convert x -> bf16+fp8; [NXB,NXB+32) pack B into MFMA-fragment
// order; last block zeros gcur + pooled_pad. One launch instead of four.
__global__ __launch_bounds__(256)
void prep(const float* __restrict__ x, unsigned short* __restrict__ xb,
          unsigned char* __restrict__ x8,
          const float* __restrict__ Wr2, const float* __restrict__ Wl2,
          unsigned short* __restrict__ Bsw,
          int* __restrict__ gcur, float* __restrict__ pooled_pad,
          long n16, int NXB, int NCB) {
    const int bid = blockIdx.x;
    const int tid = threadIdx.x;
    if (bid < NXB) {
        const long t = (long)bid * 256 + tid;
        if (t >= n16) return;
        const float4* x4 = (const float4*)x;
        float4 v0 = x4[t * 4], v1 = x4[t * 4 + 1], v2 = x4[t * 4 + 2], v3 = x4[t * 4 + 3];
        uint2 p0 = pack4(v0), p1 = pack4(v1), p2 = pack4(v2), p3 = pack4(v3);
        ((uint4*)xb)[t * 2]     = make_uint4(p0.x, p0.y, p1.x, p1.y);
        ((uint4*)xb)[t * 2 + 1] = make_uint4(p2.x, p2.y, p3.x, p3.y);
        ((uint4*)x8)[t] = make_uint4(packfp8(v0), packfp8(v1), packfp8(v2), packfp8(v3));
    } else if (bid < NXB + 32) {
        // Bsw[(((kk*4+wn2)*4+t)*64+lane)*8+e] = B[wn2*64+t*16+(lane&15)][kk*32+(lane>>4)*8+e]
        const int t_idx = (bid - NXB) * 256 + tid;
        const int lane = t_idx & 63;
        const int rest = t_idx >> 6;
        const int tt   = rest & 3;
        const int wn2  = (rest >> 2) & 3;
        const int kk   = rest >> 4;
        const int j = wn2 * 64 + tt * 16 + (lane & 15);
        const int k = kk * 32 + (lane >> 4) * 8;
        const float* src = (k < 128) ? &Wr2[j * 128 + k] : &Wl2[j * 128 + (k - 128)];
        float4 v0 = *(const float4*)src;
        float4 v1 = *(const float4*)(src + 4);
        uint2 p0 = pack4(v0), p1 = pack4(v1);
        *(uint4*)&Bsw[(long)t_idx * 8] = make_uint4(p0.x, p0.y, p1.x, p1.y);
    } else {
        for (int i = tid; i < NCB * 16; i += 256) gcur[i] = 0;
        for (int i = tid; i < 256 * 16; i += 256) pooled_pad[i] = 0.f;
    }
}

// Stage 1: coarse binning with 64B-exclusive writes (two-pass count/alloc/scatter).
// int64-vs-int32 edge dtype detected inline by wave 0 (hi dwords of first 64 entries).
__global__ __launch_bounds__(256)
void coarse_bin(const void* __restrict__ ei, int* __restrict__ gcur,
                unsigned* __restrict__ segc, int E, int NCB) {
    __shared__ int cnt[256];
    __shared__ int basel[256];
    __shared__ int s_is64;
    const int tid = threadIdx.x;
    const long e0 = (long)blockIdx.x * EPB;
    const int ecnt = (int)min((long)EPB, (long)E - e0);

    if (tid < 64) {
        const int v = ((const int*)ei)[2 * tid + 1];
        const unsigned long long b = __ballot(v != 0);
        if (tid == 0) s_is64 = (b == 0ull);
    }
    for (int i = tid; i < NCB; i += 256) cnt[i] = 0;
    __syncthreads();
    const int is64 = s_is64;

    for (int j = tid; j < ecnt; j += 256) {
        int t = is64 ? (int)((const long long*)ei)[E + e0 + j]
                     : ((const int*)ei)[E + e0 + j];
        atomicAdd(&cnt[t >> CBITS], 1);
    }
    __syncthreads();

    for (int c = tid; c < NCB; c += 256) {
        const int n = cnt[c];
        const int na = (n + 15) & ~15;
        int b = 0;
        if (na > 0) b = atomicAdd(&gcur[c * 16], na);
        basel[c] = b;
        cnt[c] = 0;
        unsigned* sp = segc + (long)c * CCAP;
        for (int i = n; i < na; ++i)
            if (b + i < CCAP) sp[b + i] = 0xFFFFFFFFu;
    }
    __syncthreads();

    for (int j = tid; j < ecnt; j += 256) {
        int s, t;
        if (is64) { const long long* p = (const long long*)ei; s = (int)p[e0 + j]; t = (int)p[E + e0 + j]; }
        else      { const int* p = (const int*)ei;             s = p[e0 + j];      t = p[E + e0 + j]; }
        const int c = t >> CBITS;
        const int r = atomicAdd(&cnt[c], 1);
        const int pos = basel[c] + r;
        if (pos < CCAP)
            segc[(long)c * CCAP + pos] = ((unsigned)s << CBITS) | (unsigned)(t & (CSIZE - 1));
    }
}

// Stage 2: per coarse bucket, histogram + scan + scatter -> dense node-ordered gorder.
__global__ __launch_bounds__(1024)
void refine(const int* __restrict__ gcur, const unsigned* __restrict__ segc,
            unsigned* __restrict__ gorder, int2* __restrict__ rowdeg, int M) {
    __shared__ unsigned order[CCAP];            // 40 KB
    __shared__ int degh[CSIZE], scn[CSIZE], cur[CSIZE];
    const int tid = threadIdx.x;
    const int cb = blockIdx.x;
    const int nbase = cb << CBITS;
    const int nn = min(CSIZE, M - nbase);
    const int len = min(gcur[cb * 16], CCAP);
    const unsigned* sp = segc + (long)cb * CCAP;

    if (tid < CSIZE) degh[tid] = 0;
    __syncthreads();
    for (int i = tid; i < len; i += 1024) {
        const unsigned e = sp[i];
        if (e != 0xFFFFFFFFu) atomicAdd(&degh[e & (CSIZE - 1)], 1);
    }
    __syncthreads();
    if (tid < CSIZE) scn[tid] = degh[tid];
    __syncthreads();
    for (int off = 1; off < CSIZE; off <<= 1) {
        int v = 0;
        if (tid >= off && tid < CSIZE) v = scn[tid - off];
        __syncthreads();
        if (tid < CSIZE) scn[tid] += v;
        __syncthreads();
    }
    if (tid < CSIZE) cur[tid] = scn[tid] - degh[tid];
    __syncthreads();
    for (int i = tid; i < len; i += 1024) {
        const unsigned e = sp[i];
        if (e != 0xFFFFFFFFu) {
            const int r = atomicAdd(&cur[e & (CSIZE - 1)], 1);
            order[r] = e >> CBITS;
        }
    }
    __syncthreads();
    const int total = scn[CSIZE - 1];
    unsigned* gp = gorder + (long)cb * CCAP;
    for (int i = tid; i < total; i += 1024) gp[i] = order[i];
    if (tid < nn)
        rowdeg[nbase + tid] = make_int2(cb * CCAP + (scn[tid] - degh[tid]), degh[tid]);
}

// Stage 3: per 128-node tile: stage order slice into LDS, fp8 register gather.
__global__ __launch_bounds__(1024)
void gather_tile(const unsigned char* __restrict__ x8, const unsigned* __restrict__ gorder,
                 const int2* __restrict__ rowdeg, unsigned short* __restrict__ aggb, int M) {
    __shared__ unsigned ordl[GT_CAP];           // 16 KB
    __shared__ int s_start, s_total;
    const int tid = threadIdx.x;
    const int first = blockIdx.x * 128;
    const int nn = min(128, M - first);

    if (tid == 0) {
        int2 r0 = rowdeg[first];
        int2 rl = rowdeg[first + nn - 1];
        s_start = r0.x;
        s_total = min(rl.x + rl.y - r0.x, GT_CAP);
    }
    __syncthreads();
    const int st = s_start, tot = s_total;
    for (int i = tid; i < tot; i += 1024) ordl[i] = gorder[st + i];
    __syncthreads();

    const int wave = tid >> 6;
    const int lane = tid & 63;
    const int sub = lane >> 5;
    const int c   = lane & 31;
    const unsigned* x32 = (const unsigned*)x8;   // row = 32 uints
    unsigned* ab32 = (unsigned*)aggb;            // row = 64 uints (bf16)

    for (int nl = wave; nl < nn; nl += 16) {
        const long node = (long)first + nl;
        const int2 rd = rowdeg[node];
        const int beg = rd.x - st;
        const int deg = min(rd.y, tot - beg);
        float a0 = 0.f, a1 = 0.f, a2 = 0.f, a3 = 0.f;
        int i = 0;
        for (; i + 8 <= deg; i += 8) {
            unsigned v0 = x32[(long)ordl[beg + i + sub]     * 32 + c];
            unsigned v1 = x32[(long)ordl[beg + i + 2 + sub] * 32 + c];
            unsigned v2 = x32[(long)ordl[beg + i + 4 + sub] * 32 + c];
            unsigned v3 = x32[(long)ordl[beg + i + 6 + sub] * 32 + c];
            f32x2 l0 = __builtin_amdgcn_cvt_pk_f32_fp8(v0, false);
            f32x2 h0 = __builtin_amdgcn_cvt_pk_f32_fp8(v0, true);
            f32x2 l1 = __builtin_amdgcn_cvt_pk_f32_fp8(v1, false);
            f32x2 h1 = __builtin_amdgcn_cvt_pk_f32_fp8(v1, true);
            f32x2 l2 = __builtin_amdgcn_cvt_pk_f32_fp8(v2, false);
            f32x2 h2 = __builtin_amdgcn_cvt_pk_f32_fp8(v2, true);
            f32x2 l3 = __builtin_amdgcn_cvt_pk_f32_fp8(v3, false);
            f32x2 h3 = __builtin_amdgcn_cvt_pk_f32_fp8(v3, true);
            a0 += l0.x + l1.x + l2.x + l3.x;
            a1 += l0.y + l1.y + l2.y + l3.y;
            a2 += h0.x + h1.x + h2.x + h3.x;
            a3 += h0.y + h1.y + h2.y + h3.y;
        }
        for (; i + 2 <= deg; i += 2) {
            unsigned v = x32[(long)ordl[beg + i + sub] * 32 + c];
            f32x2 lo = __builtin_amdgcn_cvt_pk_f32_fp8(v, false);
            f32x2 hi = __builtin_amdgcn_cvt_pk_f32_fp8(v, true);
            a0 += lo.x; a1 += lo.y; a2 += hi.x; a3 += hi.y;
        }
        if (i < deg && sub == 0) {
            unsigned v = x32[(long)ordl[beg + i] * 32 + c];
            f32x2 lo = __builtin_amdgcn_cvt_pk_f32_fp8(v, false);
            f32x2 hi = __builtin_amdgcn_cvt_pk_f32_fp8(v, true);
            a0 += lo.x; a1 += lo.y; a2 += hi.x; a3 += hi.y;
        }
        a0 += __shfl_xor(a0, 32);
        a1 += __shfl_xor(a1, 32);
        a2 += __shfl_xor(a2, 32);
        a3 += __shfl_xor(a3, 32);
        if (sub == 0) {
            const float rd2 = 1.0f / fmaxf((float)rd.y, 1.0f);
            unsigned w0 = (unsigned)f2bf(a0 * rd2) | ((unsigned)f2bf(a1 * rd2) << 16);
            unsigned w1 = (unsigned)f2bf(a2 * rd2) | ((unsigned)f2bf(a3 * rd2) << 16);
            *(uint2*)&ab32[node * 64 + c * 2] = make_uint2(w0, w1);
        }
    }
}

// GEMM v4: T3+T4 pipelined M-loop. 512 resident blocks (2/CU), each grid-strides
// over 32-row x 256-col tiles. A staged into a 4-deep LDS ring (4 x 16 KB) via
// async global_load_lds; counted s_waitcnt vmcnt(8) (never 0 in steady state) +
// ONE raw s_barrier per tile. B (128 KB, L2-hot) + bias hoisted into registers
// once per block, so the steady-state loop's ONLY vmem ops are the 4 staging
// g2lds per wave -> counted vmcnt is exact. Pool accumulates in registers across
// tiles; single atomic flush per block. Source chunks XOR-swizzled (cs = cl^rw)
// so the linear LDS dest reads back with the same involution on ds_read_b128.
__global__ __launch_bounds__(256, 2)
void gemm_pool(const unsigned short* __restrict__ xb, const unsigned short* __restrict__ aggb,
               const unsigned short* __restrict__ Bsw, const float* __restrict__ bias2,
               float* __restrict__ pooled_pad, int M, int NT) {
    __shared__ unsigned short As[4 * 32 * 256];   // 64 KB: 4 bufs x (32 rows x 512 B)
    const int tid  = threadIdx.x;
    const int lane = tid & 63;
    const int wn2  = tid >> 6;        // wave = 64-col group 0..3
    const int lrow = lane & 15;
    const int quad = lane >> 4;
    const int bid  = blockIdx.x;
    const int GRID = gridDim.x;
    const int nt   = (NT - bid + GRID - 1) / GRID;   // tiles for this block (uniform)
    if (nt <= 0) return;

    // ---- B frags (32 x uint4 = 128 VGPR) + bias, once per block (L2-hot) ----
    uint4 bb[8][4];
    #pragma unroll
    for (int kk = 0; kk < 8; ++kk)
        #pragma unroll
        for (int t = 0; t < 4; ++t)
            bb[kk][t] = *(const uint4*)&Bsw[((((long)kk * 4 + wn2) * 4 + t) * 64 + lane) * 8];
    float bv[4];
    #pragma unroll
    for (int t = 0; t < 4; ++t) bv[t] = bias2[wn2 * 64 + t * 16 + lrow];

    // staging constants: thread covers (row%8 = rw, LDS chunk cl), source chunk cl^rw
    const int cl = tid & 31;
    const int rw = tid >> 5;
    const int cs = cl ^ rw;
    const unsigned short* sbase = (cs < 16) ? (xb + (long)cs * 8)
                                            : (aggb + (long)(cs - 16) * 8);
    char* lbase = (char*)As + rw * 512 + cl * 16;

    auto STAGE = [&](int p) {
        const long trow = ((long)bid + (long)p * GRID) * 32;
        char* ld = lbase + (p & 3) * 16384;
        #pragma unroll
        for (int s = 0; s < 4; ++s)
            g2lds16(sbase + (trow + s * 8 + rw) * 128, ld + s * 4096);
    };

    #pragma unroll
    for (int p = 0; p < 3; ++p) if (p < nt) STAGE(p);

    float ps[4] = {0.f, 0.f, 0.f, 0.f};

    for (int p = 0; p < nt; ++p) {
        const int rem = nt - 1 - p;
        if (rem >= 2)      asm volatile("s_waitcnt vmcnt(8)" ::: "memory");
        else if (rem == 1) asm volatile("s_waitcnt vmcnt(4)" ::: "memory");
        else               asm volatile("s_waitcnt vmcnt(0)" ::: "memory");
        __builtin_amdgcn_s_barrier();
        if (p + 3 < nt) STAGE(p + 3);   // 12 wave-loads in flight during compute

        const char* Ab = (const char*)As + (p & 3) * 16384;
        f32x4 acc[2][4] = {};
        #pragma unroll
        for (int kk = 0; kk < 8; ++kk) {
            uint4 aC[2];
            #pragma unroll
            for (int i = 0; i < 2; ++i) {
                const int r = i * 16 + lrow;   // r&7 == lrow&7
                aC[i] = *(const uint4*)(Ab + r * 512 + (((kk * 4 + quad) ^ (lrow & 7)) * 16));
            }
            #pragma unroll
            for (int i = 0; i < 2; ++i)
                #pragma unroll
                for (int t = 0; t < 4; ++t)
                    acc[i][t] = __builtin_amdgcn_mfma_f32_16x16x32_bf16(
                        *(bf16x8*)&aC[i], *(bf16x8*)&bb[kk][t], acc[i][t], 0, 0, 0);
        }

        // bias + ReLU + masked row-sum, accumulated in registers across tiles
        const long trow = ((long)bid + (long)p * GRID) * 32;
        #pragma unroll
        for (int t = 0; t < 4; ++t) {
            float s = 0.f;
            #pragma unroll
            for (int i = 0; i < 2; ++i) {
                const long rbase = trow + i * 16 + quad * 4;
                #pragma unroll
                for (int r = 0; r < 4; ++r) {
                    float h = fmaxf(acc[i][t][r] + bv[t], 0.f);
                    if (rbase + r < M) s += h;
                }
            }
            ps[t] += s;
        }
    }

    // single pooled flush per block
    #pragma unroll
    for (int t = 0; t < 4; ++t) {
        ps[t] += __shfl_xor(ps[t], 16);
        ps[t] += __shfl_xor(ps[t], 32);
        if (quad == 0)
            atomicAdd(&pooled_pad[(wn2 * 64 + t * 16 + lrow) * 16], ps[t]);
    }
}

// pooled -> MLP head -> log_softmax. One block, 256 threads.
__global__ __launch_bounds__(256)
void head_kernel(const float* __restrict__ pooled_pad,
                 const float* __restrict__ W1, const float* __restrict__ b1,
                 const float* __restrict__ W2, const float* __restrict__ b2,
                 float* __restrict__ out, float invM) {
    __shared__ float pooled_s[256];
    __shared__ float z1_s[256];
    __shared__ float z2_s[10];
    const int j = threadIdx.x;

    pooled_s[j] = pooled_pad[j * 16] * invM;
    __syncthreads();

    const float4* w4 = (const float4*)(W1 + (long)j * 256);
    float sx = 0.f, sy = 0.f, sz = 0.f, sw = 0.f;
    #pragma unroll 8
    for (int k = 0; k < 64; ++k) {
        float4 w = w4[k];
        float4 p = *(const float4*)&pooled_s[k * 4];
        sx += w.x * p.x; sy += w.y * p.y; sz += w.z * p.z; sw += w.w * p.w;
    }
    z1_s[j] = fmaxf(b1[j] + sx + sy + sz + sw, 0.f);
    __syncthreads();

    if (j < 160) {
        const int c = j >> 4, q = j & 15;
        float s = 0.f;
        for (int k = q; k < 256; k += 16) s += W2[c * 256 + k] * z1_s[k];
        #pragma unroll
        for (int off = 8; off >= 1; off >>= 1) s += __shfl_down(s, off, 16);
        if (q == 0) z2_s[c] = s + b2[c];
    }
    __syncthreads();

    if (j == 0) {
        float mx = z2_s[0];
        for (int c = 1; c < 10; ++c) mx = fmaxf(mx, z2_s[c]);
        float se = 0.f;
        for (int c = 0; c < 10; ++c) se += expf(z2_s[c] - mx);
        const float ls = logf(se);
        for (int c = 0; c < 10; ++c) out[c] = z2_s[c] - mx - ls;
    }
}

extern "C" void kernel_launch(void* const* d_in, const int* in_sizes, int n_in,
                              void* d_out, int out_size, void* d_ws, size_t ws_size,
                              hipStream_t stream) {
    const float* x    = (const float*)d_in[0];
    const void*  ei   = d_in[1];
    const float* Wl   = (const float*)d_in[2];
    const float* Wr   = (const float*)d_in[3];
    const float* bias = (const float*)d_in[4];
    const float* W1   = (const float*)d_in[5];
    const float* b1   = (const float*)d_in[6];
    const float* W2   = (const float*)d_in[7];
    const float* b2   = (const float*)d_in[8];
    float* out = (float*)d_out;

    const int M = in_sizes[0] / D_IN;        // 100000 nodes
    const int E = in_sizes[1] / 2;           // 1.6M edges
    const int L = in_sizes[4] / D_HID;       // 3 layers
    const int NMB = (M + 127) / 128;         // 128-node tiles (782)
    const long Mpad = (long)NMB * 128;       // row-padded region size (GEMM OOB-safe)
    const int NCB = (M + CSIZE - 1) / CSIZE; // coarse buckets (196)
    const int NB1 = (E + EPB - 1) / EPB;     // coarse_bin blocks (196)
    const int NT  = (M + 31) / 32;           // gemm 32-row tiles (3125)
    const int NG  = (NT < 512) ? NT : 512;   // resident grid: 2 blocks/CU

    // Only the LAST layer matters (h is overwritten each loop iteration).
    const float* Wl2   = Wl + (long)(L - 1) * D_HID * D_IN;
    const float* Wr2   = Wr + (long)(L - 1) * D_HID * D_IN;
    const float* bias2 = bias + (long)(L - 1) * D_HID;

    // workspace: xb[Mpad*128]bf16 | aggb[Mpad*128]bf16 | x8[Mpad*128]u8 | Bsw[256*256]bf16 |
    //            pooled_pad[256*16]f | gcur[NCB*16]i | segc[NCB*CCAP]u | gorder[NCB*CCAP]u |
    //            rowdeg[M]int2   (pad rows of xb/aggb are garbage; GEMM masks rows >= M)
    unsigned short* xb   = (unsigned short*)d_ws;
    unsigned short* aggb = xb + Mpad * D_IN;
    unsigned char*  x8   = (unsigned char*)(aggb + Mpad * D_IN);
    unsigned short* Bsw  = (unsigned short*)(x8 + Mpad * D_IN);
    float* pooled_pad    = (float*)(Bsw + 256 * 256);
    int*      gcur       = (int*)(pooled_pad + 256 * 16);
    unsigned* segc       = (unsigned*)(gcur + (long)NCB * 16);
    unsigned* gorder     = segc + (long)NCB * CCAP;
    int2*     rowdeg     = (int2*)(gorder + (long)NCB * CCAP);

    const long n16 = (long)M * 8;            // 16-float chunks of x
    const int NXB = (int)((n16 + 255) / 256);

    prep<<<NXB + 32 + 1, 256, 0, stream>>>(x, xb, x8, Wr2, Wl2, Bsw, gcur, pooled_pad,
                                           n16, NXB, NCB);
    coarse_bin<<<NB1, 256, 0, stream>>>(ei, gcur, segc, E, NCB);
    refine<<<NCB, 1024, 0, stream>>>(gcur, segc, gorder, rowdeg, M);
    gather_tile<<<NMB, 1024, 0, stream>>>(x8, gorder, rowdeg, aggb, M);

    gemm_pool<<<NG, 256, 0, stream>>>(xb, aggb, Bsw, bias2, pooled_pad, M, NT);

    head_kernel<<<1, 256, 0, stream>>>(pooled_pad, W1, b1, W2, b2, out, 1.0f / (float)M);
}

// Round 3
// 238.803 us; speedup vs baseline: 1.1638x; 1.0065x over previous
//
#include <hip/hip_runtime.h>
#include <hip/hip_bf16.h>

#define D_IN  128
#define D_HID 256
#define CBITS 9
#define CSIZE 512          // nodes per coarse bucket
#define EPB   8192         // edges per coarse_bin block
#define CCAP  10240        // entry capacity per coarse bucket (mean ~9630 + slack)
#define GT_CAP 2048        // LDS order-tile capacity for a 64-node gather tile

typedef __bf16 bf16x8 __attribute__((ext_vector_type(8)));
typedef float  f32x4  __attribute__((ext_vector_type(4)));
typedef float  f32x2  __attribute__((ext_vector_type(2)));

__device__ __forceinline__ unsigned short f2bf(float f) {
    unsigned u = __float_as_uint(f);
    u += 0x7FFFu + ((u >> 16) & 1u);   // RNE
    return (unsigned short)(u >> 16);
}
__device__ __forceinline__ uint2 pack4(float4 v) {
    unsigned lo = (unsigned)f2bf(v.x) | ((unsigned)f2bf(v.y) << 16);
    unsigned hi = (unsigned)f2bf(v.z) | ((unsigned)f2bf(v.w) << 16);
    return make_uint2(lo, hi);
}
// pack 4 floats -> 4 fp8 e4m3 bytes (HW cvt)
__device__ __forceinline__ unsigned packfp8(float4 v) {
    int u = __builtin_amdgcn_cvt_pk_fp8_f32(v.x, v.y, 0, false);
    u = __builtin_amdgcn_cvt_pk_fp8_f32(v.z, v.w, u, true);
    return (unsigned)u;
}
// async 16B global -> LDS (vmcnt)
__device__ __forceinline__ void g2lds16(const void* g, void* l) {
    __builtin_amdgcn_global_load_lds(
        (const __attribute__((address_space(1))) unsigned int*)g,
        (__attribute__((address_space(3))) unsigned int*)l, 16, 0, 0);
}

// Fused prep: [0,NXB) convert x -> bf16+fp8; [NXB,NXB+32) pack B into MFMA-fragment
// order; last block zeros gcur + pooled_pad. One launch instead of four.
__global__ __launch_bounds__(256)
void prep(const float* __restrict__ x, unsigned short* __restrict__ xb,
          unsigned char* __restrict__ x8,
          const float* __restrict__ Wr2, const float* __restrict__ Wl2,
          unsigned short* __restrict__ Bsw,
          int* __restrict__ gcur, float* __restrict__ pooled_pad,
          long n16, int NXB, int NCB) {
    const int bid = blockIdx.x;
    const int tid = threadIdx.x;
    if (bid < NXB) {
        const long t = (long)bid * 256 + tid;
        if (t >= n16) return;
        const float4* x4 = (const float4*)x;
        float4 v0 = x4[t * 4], v1 = x4[t * 4 + 1], v2 = x4[t * 4 + 2], v3 = x4[t * 4 + 3];
        uint2 p0 = pack4(v0), p1 = pack4(v1), p2 = pack4(v2), p3 = pack4(v3);
        ((uint4*)xb)[t * 2]     = make_uint4(p0.x, p0.y, p1.x, p1.y);
        ((uint4*)xb)[t * 2 + 1] = make_uint4(p2.x, p2.y, p3.x, p3.y);
        ((uint4*)x8)[t] = make_uint4(packfp8(v0), packfp8(v1), packfp8(v2), packfp8(v3));
    } else if (bid < NXB + 32) {
        // Bsw[(((kk*4+wn2)*4+t)*64+lane)*8+e] = B[wn2*64+t*16+(lane&15)][kk*32+(lane>>4)*8+e]
        const int t_idx = (bid - NXB) * 256 + tid;
        const int lane = t_idx & 63;
        const int rest = t_idx >> 6;
        const int tt   = rest & 3;
        const int wn2  = (rest >> 2) & 3;
        const int kk   = rest >> 4;
        const int j = wn2 * 64 + tt * 16 + (lane & 15);
        const int k = kk * 32 + (lane >> 4) * 8;
        const float* src = (k < 128) ? &Wr2[j * 128 + k] : &Wl2[j * 128 + (k - 128)];
        float4 v0 = *(const float4*)src;
        float4 v1 = *(const float4*)(src + 4);
        uint2 p0 = pack4(v0), p1 = pack4(v1);
        *(uint4*)&Bsw[(long)t_idx * 8] = make_uint4(p0.x, p0.y, p1.x, p1.y);
    } else {
        for (int i = tid; i < NCB * 16; i += 256) gcur[i] = 0;
        for (int i = tid; i < 256 * 16; i += 256) pooled_pad[i] = 0.f;
    }
}

// Stage 1: coarse binning with 64B-exclusive writes (two-pass count/alloc/scatter).
// int64-vs-int32 edge dtype detected inline by wave 0 (hi dwords of first 64 entries).
__global__ __launch_bounds__(256)
void coarse_bin(const void* __restrict__ ei, int* __restrict__ gcur,
                unsigned* __restrict__ segc, int E, int NCB) {
    __shared__ int cnt[256];
    __shared__ int basel[256];
    __shared__ int s_is64;
    const int tid = threadIdx.x;
    const long e0 = (long)blockIdx.x * EPB;
    const int ecnt = (int)min((long)EPB, (long)E - e0);

    if (tid < 64) {
        const int v = ((const int*)ei)[2 * tid + 1];
        const unsigned long long b = __ballot(v != 0);
        if (tid == 0) s_is64 = (b == 0ull);
    }
    for (int i = tid; i < NCB; i += 256) cnt[i] = 0;
    __syncthreads();
    const int is64 = s_is64;

    for (int j = tid; j < ecnt; j += 256) {
        int t = is64 ? (int)((const long long*)ei)[E + e0 + j]
                     : ((const int*)ei)[E + e0 + j];
        atomicAdd(&cnt[t >> CBITS], 1);
    }
    __syncthreads();

    for (int c = tid; c < NCB; c += 256) {
        const int n = cnt[c];
        const int na = (n + 15) & ~15;
        int b = 0;
        if (na > 0) b = atomicAdd(&gcur[c * 16], na);
        basel[c] = b;
        cnt[c] = 0;
        unsigned* sp = segc + (long)c * CCAP;
        for (int i = n; i < na; ++i)
            if (b + i < CCAP) sp[b + i] = 0xFFFFFFFFu;
    }
    __syncthreads();

    for (int j = tid; j < ecnt; j += 256) {
        int s, t;
        if (is64) { const long long* p = (const long long*)ei; s = (int)p[e0 + j]; t = (int)p[E + e0 + j]; }
        else      { const int* p = (const int*)ei;             s = p[e0 + j];      t = p[E + e0 + j]; }
        const int c = t >> CBITS;
        const int r = atomicAdd(&cnt[c], 1);
        const int pos = basel[c] + r;
        if (pos < CCAP)
            segc[(long)c * CCAP + pos] = ((unsigned)s << CBITS) | (unsigned)(t & (CSIZE - 1));
    }
}

// Stage 2: per coarse bucket, histogram + scan + scatter -> dense node-ordered gorder.
// gorder entries are pre-scaled to BYTE offsets into x8 (src*128) so the gather
// kernel does pure 32-bit addressing.
__global__ __launch_bounds__(1024)
void refine(const int* __restrict__ gcur, const unsigned* __restrict__ segc,
            unsigned* __restrict__ gorder, int2* __restrict__ rowdeg, int M) {
    __shared__ unsigned order[CCAP];            // 40 KB
    __shared__ int degh[CSIZE], scn[CSIZE], cur[CSIZE];
    const int tid = threadIdx.x;
    const int cb = blockIdx.x;
    const int nbase = cb << CBITS;
    const int nn = min(CSIZE, M - nbase);
    const int len = min(gcur[cb * 16], CCAP);
    const unsigned* sp = segc + (long)cb * CCAP;

    if (tid < CSIZE) degh[tid] = 0;
    __syncthreads();
    for (int i = tid; i < len; i += 1024) {
        const unsigned e = sp[i];
        if (e != 0xFFFFFFFFu) atomicAdd(&degh[e & (CSIZE - 1)], 1);
    }
    __syncthreads();
    if (tid < CSIZE) scn[tid] = degh[tid];
    __syncthreads();
    for (int off = 1; off < CSIZE; off <<= 1) {
        int v = 0;
        if (tid >= off && tid < CSIZE) v = scn[tid - off];
        __syncthreads();
        if (tid < CSIZE) scn[tid] += v;
        __syncthreads();
    }
    if (tid < CSIZE) cur[tid] = scn[tid] - degh[tid];
    __syncthreads();
    for (int i = tid; i < len; i += 1024) {
        const unsigned e = sp[i];
        if (e != 0xFFFFFFFFu) {
            const int r = atomicAdd(&cur[e & (CSIZE - 1)], 1);
            order[r] = (e >> CBITS) << 7;       // src * 128 = byte offset into x8
        }
    }
    __syncthreads();
    const int total = scn[CSIZE - 1];
    unsigned* gp = gorder + (long)cb * CCAP;
    for (int i = tid; i < total; i += 1024) gp[i] = order[i];
    if (tid < nn)
        rowdeg[nbase + tid] = make_int2(cb * CCAP + (scn[tid] - degh[tid]), degh[tid]);
}

// Stage 3 v2: per 64-node tile (512 thr, 8 waves; 4 blocks/CU). Lane = (c2,sub):
// c2 = uint2 column (8 fp8 channels), sub = edge slot. One load inst covers
// 4 rows x 128 B = 512 B; f32x2 accumulators use v_pk_add_f32; gorder holds
// pre-scaled byte offsets -> pure 32-bit addressing. ~22 VALU / 8 edges / lane
// (was ~40 at 4 B/lane).
__global__ __launch_bounds__(512)
void gather_tile(const unsigned char* __restrict__ x8, const unsigned* __restrict__ gorder,
                 const int2* __restrict__ rowdeg, unsigned short* __restrict__ aggb, int M) {
    __shared__ unsigned ordl[GT_CAP];           // 8 KB (byte offsets)
    __shared__ int s_start, s_total;
    const int tid = threadIdx.x;
    const int first = blockIdx.x * 64;
    const int nn = min(64, M - first);

    if (tid == 0) {
        int2 r0 = rowdeg[first];
        int2 rl = rowdeg[first + nn - 1];
        s_start = r0.x;
        s_total = min(rl.x + rl.y - r0.x, GT_CAP);
    }
    __syncthreads();
    const int st = s_start, tot = s_total;
    for (int i = tid; i < tot; i += 512) ordl[i] = gorder[st + i];
    __syncthreads();

    const int wave = tid >> 6;       // 0..7
    const int lane = tid & 63;
    const int c2   = lane & 15;      // uint2 column: channels c2*8 .. c2*8+7
    const int sub  = lane >> 4;      // 0..3 edge slot
    const unsigned cb = (unsigned)c2 * 8;

    for (int nl = wave; nl < nn; nl += 8) {
        const int node = first + nl;
        const int2 rd = rowdeg[node];
        const int beg = rd.x - st;
        const int deg = min(rd.y, tot - beg);
        f32x2 a0 = {0.f, 0.f}, a1 = {0.f, 0.f}, a2 = {0.f, 0.f}, a3 = {0.f, 0.f};
        int i = 0;
        const int nf = deg & ~7;
        for (; i < nf; i += 8) {
            uint2 v0 = *(const uint2*)(x8 + (ordl[beg + i + sub] + cb));
            uint2 v1 = *(const uint2*)(x8 + (ordl[beg + i + 4 + sub] + cb));
            a0 += __builtin_amdgcn_cvt_pk_f32_fp8(v0.x, false);
            a1 += __builtin_amdgcn_cvt_pk_f32_fp8(v0.x, true);
            a2 += __builtin_amdgcn_cvt_pk_f32_fp8(v0.y, false);
            a3 += __builtin_amdgcn_cvt_pk_f32_fp8(v0.y, true);
            a0 += __builtin_amdgcn_cvt_pk_f32_fp8(v1.x, false);
            a1 += __builtin_amdgcn_cvt_pk_f32_fp8(v1.x, true);
            a2 += __builtin_amdgcn_cvt_pk_f32_fp8(v1.y, false);
            a3 += __builtin_amdgcn_cvt_pk_f32_fp8(v1.y, true);
        }
        if (i < deg) {
            uint2 v0 = (i + sub < deg)
                     ? *(const uint2*)(x8 + (ordl[beg + i + sub] + cb)) : make_uint2(0, 0);
            uint2 v1 = (i + 4 + sub < deg)
                     ? *(const uint2*)(x8 + (ordl[beg + i + 4 + sub] + cb)) : make_uint2(0, 0);
            a0 += __builtin_amdgcn_cvt_pk_f32_fp8(v0.x, false);
            a1 += __builtin_amdgcn_cvt_pk_f32_fp8(v0.x, true);
            a2 += __builtin_amdgcn_cvt_pk_f32_fp8(v0.y, false);
            a3 += __builtin_amdgcn_cvt_pk_f32_fp8(v0.y, true);
            a0 += __builtin_amdgcn_cvt_pk_f32_fp8(v1.x, false);
            a1 += __builtin_amdgcn_cvt_pk_f32_fp8(v1.x, true);
            a2 += __builtin_amdgcn_cvt_pk_f32_fp8(v1.y, false);
            a3 += __builtin_amdgcn_cvt_pk_f32_fp8(v1.y, true);
        }
        // reduce over sub groups (lanes c2, c2+16, c2+32, c2+48)
        a0.x += __shfl_xor(a0.x, 16); a0.x += __shfl_xor(a0.x, 32);
        a0.y += __shfl_xor(a0.y, 16); a0.y += __shfl_xor(a0.y, 32);
        a1.x += __shfl_xor(a1.x, 16); a1.x += __shfl_xor(a1.x, 32);
        a1.y += __shfl_xor(a1.y, 16); a1.y += __shfl_xor(a1.y, 32);
        a2.x += __shfl_xor(a2.x, 16); a2.x += __shfl_xor(a2.x, 32);
        a2.y += __shfl_xor(a2.y, 16); a2.y += __shfl_xor(a2.y, 32);
        a3.x += __shfl_xor(a3.x, 16); a3.x += __shfl_xor(a3.x, 32);
        a3.y += __shfl_xor(a3.y, 16); a3.y += __shfl_xor(a3.y, 32);
        if (sub == 0) {
            const float rdiv = 1.0f / fmaxf((float)rd.y, 1.0f);
            unsigned w0 = (unsigned)f2bf(a0.x * rdiv) | ((unsigned)f2bf(a0.y * rdiv) << 16);
            unsigned w1 = (unsigned)f2bf(a1.x * rdiv) | ((unsigned)f2bf(a1.y * rdiv) << 16);
            unsigned w2 = (unsigned)f2bf(a2.x * rdiv) | ((unsigned)f2bf(a2.y * rdiv) << 16);
            unsigned w3 = (unsigned)f2bf(a3.x * rdiv) | ((unsigned)f2bf(a3.y * rdiv) << 16);
            *(uint4*)(aggb + (long)node * 128 + c2 * 8) = make_uint4(w0, w1, w2, w3);
        }
    }
}

// GEMM v4: T3+T4 pipelined M-loop. 512 resident blocks (2/CU), each grid-strides
// over 32-row x 256-col tiles. A staged into a 4-deep LDS ring (4 x 16 KB) via
// async global_load_lds; counted s_waitcnt vmcnt(8) (never 0 in steady state) +
// ONE raw s_barrier per tile. B (128 KB, L2-hot) + bias hoisted into registers
// once per block, so the steady-state loop's ONLY vmem ops are the 4 staging
// g2lds per wave -> counted vmcnt is exact. Pool accumulates in registers across
// tiles; single atomic flush per block. Source chunks XOR-swizzled (cs = cl^rw)
// so the linear LDS dest reads back with the same involution on ds_read_b128.
__global__ __launch_bounds__(256, 2)
void gemm_pool(const unsigned short* __restrict__ xb, const unsigned short* __restrict__ aggb,
               const unsigned short* __restrict__ Bsw, const float* __restrict__ bias2,
               float* __restrict__ pooled_pad, int M, int NT) {
    __shared__ unsigned short As[4 * 32 * 256];   // 64 KB: 4 bufs x (32 rows x 512 B)
    const int tid  = threadIdx.x;
    const int lane = tid & 63;
    const int wn2  = tid >> 6;        // wave = 64-col group 0..3
    const int lrow = lane & 15;
    const int quad = lane >> 4;
    const int bid  = blockIdx.x;
    const int GRID = gridDim.x;
    const int nt   = (NT - bid + GRID - 1) / GRID;   // tiles for this block (uniform)
    if (nt <= 0) return;

    // ---- B frags (32 x uint4 = 128 VGPR) + bias, once per block (L2-hot) ----
    uint4 bb[8][4];
    #pragma unroll
    for (int kk = 0; kk < 8; ++kk)
        #pragma unroll
        for (int t = 0; t < 4; ++t)
            bb[kk][t] = *(const uint4*)&Bsw[((((long)kk * 4 + wn2) * 4 + t) * 64 + lane) * 8];
    float bv[4];
    #pragma unroll
    for (int t = 0; t < 4; ++t) bv[t] = bias2[wn2 * 64 + t * 16 + lrow];

    // staging constants: thread covers (row%8 = rw, LDS chunk cl), source chunk cl^rw
    const int cl = tid & 31;
    const int rw = tid >> 5;
    const int cs = cl ^ rw;
    const unsigned short* sbase = (cs < 16) ? (xb + (long)cs * 8)
                                            : (aggb + (long)(cs - 16) * 8);
    char* lbase = (char*)As + rw * 512 + cl * 16;

    auto STAGE = [&](int p) {
        const long trow = ((long)bid + (long)p * GRID) * 32;
        char* ld = lbase + (p & 3) * 16384;
        #pragma unroll
        for (int s = 0; s < 4; ++s)
            g2lds16(sbase + (trow + s * 8 + rw) * 128, ld + s * 4096);
    };

    #pragma unroll
    for (int p = 0; p < 3; ++p) if (p < nt) STAGE(p);

    float ps[4] = {0.f, 0.f, 0.f, 0.f};

    for (int p = 0; p < nt; ++p) {
        const int rem = nt - 1 - p;
        if (rem >= 2)      asm volatile("s_waitcnt vmcnt(8)" ::: "memory");
        else if (rem == 1) asm volatile("s_waitcnt vmcnt(4)" ::: "memory");
        else               asm volatile("s_waitcnt vmcnt(0)" ::: "memory");
        __builtin_amdgcn_s_barrier();
        if (p + 3 < nt) STAGE(p + 3);   // 12 wave-loads in flight during compute

        const char* Ab = (const char*)As + (p & 3) * 16384;
        f32x4 acc[2][4] = {};
        #pragma unroll
        for (int kk = 0; kk < 8; ++kk) {
            uint4 aC[2];
            #pragma unroll
            for (int i = 0; i < 2; ++i) {
                const int r = i * 16 + lrow;   // r&7 == lrow&7
                aC[i] = *(const uint4*)(Ab + r * 512 + (((kk * 4 + quad) ^ (lrow & 7)) * 16));
            }
            #pragma unroll
            for (int i = 0; i < 2; ++i)
                #pragma unroll
                for (int t = 0; t < 4; ++t)
                    acc[i][t] = __builtin_amdgcn_mfma_f32_16x16x32_bf16(
                        *(bf16x8*)&aC[i], *(bf16x8*)&bb[kk][t], acc[i][t], 0, 0, 0);
        }

        // bias + ReLU + masked row-sum, accumulated in registers across tiles
        const long trow = ((long)bid + (long)p * GRID) * 32;
        #pragma unroll
        for (int t = 0; t < 4; ++t) {
            float s = 0.f;
            #pragma unroll
            for (int i = 0; i < 2; ++i) {
                const long rbase = trow + i * 16 + quad * 4;
                #pragma unroll
                for (int r = 0; r < 4; ++r) {
                    float h = fmaxf(acc[i][t][r] + bv[t], 0.f);
                    if (rbase + r < M) s += h;
                }
            }
            ps[t] += s;
        }
    }

    // single pooled flush per block
    #pragma unroll
    for (int t = 0; t < 4; ++t) {
        ps[t] += __shfl_xor(ps[t], 16);
        ps[t] += __shfl_xor(ps[t], 32);
        if (quad == 0)
            atomicAdd(&pooled_pad[(wn2 * 64 + t * 16 + lrow) * 16], ps[t]);
    }
}

// pooled -> MLP head -> log_softmax. One block, 256 threads.
__global__ __launch_bounds__(256)
void head_kernel(const float* __restrict__ pooled_pad,
                 const float* __restrict__ W1, const float* __restrict__ b1,
                 const float* __restrict__ W2, const float* __restrict__ b2,
                 float* __restrict__ out, float invM) {
    __shared__ float pooled_s[256];
    __shared__ float z1_s[256];
    __shared__ float z2_s[10];
    const int j = threadIdx.x;

    pooled_s[j] = pooled_pad[j * 16] * invM;
    __syncthreads();

    const float4* w4 = (const float4*)(W1 + (long)j * 256);
    float sx = 0.f, sy = 0.f, sz = 0.f, sw = 0.f;
    #pragma unroll 8
    for (int k = 0; k < 64; ++k) {
        float4 w = w4[k];
        float4 p = *(const float4*)&pooled_s[k * 4];
        sx += w.x * p.x; sy += w.y * p.y; sz += w.z * p.z; sw += w.w * p.w;
    }
    z1_s[j] = fmaxf(b1[j] + sx + sy + sz + sw, 0.f);
    __syncthreads();

    if (j < 160) {
        const int c = j >> 4, q = j & 15;
        float s = 0.f;
        for (int k = q; k < 256; k += 16) s += W2[c * 256 + k] * z1_s[k];
        #pragma unroll
        for (int off = 8; off >= 1; off >>= 1) s += __shfl_down(s, off, 16);
        if (q == 0) z2_s[c] = s + b2[c];
    }
    __syncthreads();

    if (j == 0) {
        float mx = z2_s[0];
        for (int c = 1; c < 10; ++c) mx = fmaxf(mx, z2_s[c]);
        float se = 0.f;
        for (int c = 0; c < 10; ++c) se += expf(z2_s[c] - mx);
        const float ls = logf(se);
        for (int c = 0; c < 10; ++c) out[c] = z2_s[c] - mx - ls;
    }
}

extern "C" void kernel_launch(void* const* d_in, const int* in_sizes, int n_in,
                              void* d_out, int out_size, void* d_ws, size_t ws_size,
                              hipStream_t stream) {
    const float* x    = (const float*)d_in[0];
    const void*  ei   = d_in[1];
    const float* Wl   = (const float*)d_in[2];
    const float* Wr   = (const float*)d_in[3];
    const float* bias = (const float*)d_in[4];
    const float* W1   = (const float*)d_in[5];
    const float* b1   = (const float*)d_in[6];
    const float* W2   = (const float*)d_in[7];
    const float* b2   = (const float*)d_in[8];
    float* out = (float*)d_out;

    const int M = in_sizes[0] / D_IN;        // 100000 nodes
    const int E = in_sizes[1] / 2;           // 1.6M edges
    const int L = in_sizes[4] / D_HID;       // 3 layers
    const int NMB = (M + 127) / 128;         // 128-row pad granules
    const long Mpad = (long)NMB * 128;       // row-padded region size (GEMM OOB-safe)
    const int NCB = (M + CSIZE - 1) / CSIZE; // coarse buckets (196)
    const int NB1 = (E + EPB - 1) / EPB;     // coarse_bin blocks (196)
    const int NGT = (M + 63) / 64;           // gather 64-node tiles (1563)
    const int NT  = (M + 31) / 32;           // gemm 32-row tiles (3125)
    const int NG  = (NT < 512) ? NT : 512;   // resident grid: 2 blocks/CU

    // Only the LAST layer matters (h is overwritten each loop iteration).
    const float* Wl2   = Wl + (long)(L - 1) * D_HID * D_IN;
    const float* Wr2   = Wr + (long)(L - 1) * D_HID * D_IN;
    const float* bias2 = bias + (long)(L - 1) * D_HID;

    // workspace: xb[Mpad*128]bf16 | aggb[Mpad*128]bf16 | x8[Mpad*128]u8 | Bsw[256*256]bf16 |
    //            pooled_pad[256*16]f | gcur[NCB*16]i | segc[NCB*CCAP]u | gorder[NCB*CCAP]u |
    //            rowdeg[M]int2   (pad rows of xb/aggb are garbage; GEMM masks rows >= M)
    unsigned short* xb   = (unsigned short*)d_ws;
    unsigned short* aggb = xb + Mpad * D_IN;
    unsigned char*  x8   = (unsigned char*)(aggb + Mpad * D_IN);
    unsigned short* Bsw  = (unsigned short*)(x8 + Mpad * D_IN);
    float* pooled_pad    = (float*)(Bsw + 256 * 256);
    int*      gcur       = (int*)(pooled_pad + 256 * 16);
    unsigned* segc       = (unsigned*)(gcur + (long)NCB * 16);
    unsigned* gorder     = segc + (long)NCB * CCAP;
    int2*     rowdeg     = (int2*)(gorder + (long)NCB * CCAP);

    const long n16 = (long)M * 8;            // 16-float chunks of x
    const int NXB = (int)((n16 + 255) / 256);

    prep<<<NXB + 32 + 1, 256, 0, stream>>>(x, xb, x8, Wr2, Wl2, Bsw, gcur, pooled_pad,
                                           n16, NXB, NCB);
    coarse_bin<<<NB1, 256, 0, stream>>>(ei, gcur, segc, E, NCB);
    refine<<<NCB, 1024, 0, stream>>>(gcur, segc, gorder, rowdeg, M);
    gather_tile<<<NGT, 512, 0, stream>>>(x8, gorder, rowdeg, aggb, M);

    gemm_pool<<<NG, 256, 0, stream>>>(xb, aggb, Bsw, bias2, pooled_pad, M, NT);

    head_kernel<<<1, 256, 0, stream>>>(pooled_pad, W1, b1, W2, b2, out, 1.0f / (float)M);
}

// Round 4
// 235.230 us; speedup vs baseline: 1.1815x; 1.0152x over previous
//
#include <hip/hip_runtime.h>
#include <hip/hip_bf16.h>

#define D_IN  128
#define D_HID 256
#define CBITS 7
#define CSIZE 128          // nodes per bucket (one refine_gather block)
#define EPB   8192         // edges per coarse_bin block
#define CCAP  4096         // entry capacity per bucket: mean 2048 real + ~1300 pad, +10 sigma

typedef __bf16 bf16x8 __attribute__((ext_vector_type(8)));
typedef float  f32x4  __attribute__((ext_vector_type(4)));
typedef float  f32x2  __attribute__((ext_vector_type(2)));

__device__ __forceinline__ unsigned short f2bf(float f) {
    unsigned u = __float_as_uint(f);
    u += 0x7FFFu + ((u >> 16) & 1u);   // RNE
    return (unsigned short)(u >> 16);
}
__device__ __forceinline__ uint2 pack4(float4 v) {
    unsigned lo = (unsigned)f2bf(v.x) | ((unsigned)f2bf(v.y) << 16);
    unsigned hi = (unsigned)f2bf(v.z) | ((unsigned)f2bf(v.w) << 16);
    return make_uint2(lo, hi);
}
// pack 4 floats -> 4 fp8 e4m3 bytes (HW cvt)
__device__ __forceinline__ unsigned packfp8(float4 v) {
    int u = __builtin_amdgcn_cvt_pk_fp8_f32(v.x, v.y, 0, false);
    u = __builtin_amdgcn_cvt_pk_fp8_f32(v.z, v.w, u, true);
    return (unsigned)u;
}
// async 16B global -> LDS (vmcnt)
__device__ __forceinline__ void g2lds16(const void* g, void* l) {
    __builtin_amdgcn_global_load_lds(
        (const __attribute__((address_space(1))) unsigned int*)g,
        (__attribute__((address_space(3))) unsigned int*)l, 16, 0, 0);
}
// accumulate 8 fp8 channels (one uint2) into 4 packed f32x2 accumulators
__device__ __forceinline__ void acc8(f32x2& a0, f32x2& a1, f32x2& a2, f32x2& a3, uint2 v) {
    a0 += __builtin_amdgcn_cvt_pk_f32_fp8(v.x, false);
    a1 += __builtin_amdgcn_cvt_pk_f32_fp8(v.x, true);
    a2 += __builtin_amdgcn_cvt_pk_f32_fp8(v.y, false);
    a3 += __builtin_amdgcn_cvt_pk_f32_fp8(v.y, true);
}

// Fused prep: [0,NXB) convert x -> bf16+fp8; [NXB,NXB+32) pack B into MFMA-fragment
// order; last block zeros gcur + pooled_pad. One launch instead of four.
__global__ __launch_bounds__(256)
void prep(const float* __restrict__ x, unsigned short* __restrict__ xb,
          unsigned char* __restrict__ x8,
          const float* __restrict__ Wr2, const float* __restrict__ Wl2,
          unsigned short* __restrict__ Bsw,
          int* __restrict__ gcur, float* __restrict__ pooled_pad,
          long n16, int NXB, int NCB) {
    const int bid = blockIdx.x;
    const int tid = threadIdx.x;
    if (bid < NXB) {
        const long t = (long)bid * 256 + tid;
        if (t >= n16) return;
        const float4* x4 = (const float4*)x;
        float4 v0 = x4[t * 4], v1 = x4[t * 4 + 1], v2 = x4[t * 4 + 2], v3 = x4[t * 4 + 3];
        uint2 p0 = pack4(v0), p1 = pack4(v1), p2 = pack4(v2), p3 = pack4(v3);
        ((uint4*)xb)[t * 2]     = make_uint4(p0.x, p0.y, p1.x, p1.y);
        ((uint4*)xb)[t * 2 + 1] = make_uint4(p2.x, p2.y, p3.x, p3.y);
        ((uint4*)x8)[t] = make_uint4(packfp8(v0), packfp8(v1), packfp8(v2), packfp8(v3));
    } else if (bid < NXB + 32) {
        // Bsw[(((kk*4+wn2)*4+t)*64+lane)*8+e] = B[wn2*64+t*16+(lane&15)][kk*32+(lane>>4)*8+e]
        const int t_idx = (bid - NXB) * 256 + tid;
        const int lane = t_idx & 63;
        const int rest = t_idx >> 6;
        const int tt   = rest & 3;
        const int wn2  = (rest >> 2) & 3;
        const int kk   = rest >> 4;
        const int j = wn2 * 64 + tt * 16 + (lane & 15);
        const int k = kk * 32 + (lane >> 4) * 8;
        const float* src = (k < 128) ? &Wr2[j * 128 + k] : &Wl2[j * 128 + (k - 128)];
        float4 v0 = *(const float4*)src;
        float4 v1 = *(const float4*)(src + 4);
        uint2 p0 = pack4(v0), p1 = pack4(v1);
        *(uint4*)&Bsw[(long)t_idx * 8] = make_uint4(p0.x, p0.y, p1.x, p1.y);
    } else {
        for (int i = tid; i < NCB * 16; i += 256) gcur[i] = 0;
        for (int i = tid; i < 256 * 16; i += 256) pooled_pad[i] = 0.f;
    }
}

// Stage 1: coarse binning with 64B-exclusive writes (two-pass count/alloc/scatter).
// int64-vs-int32 edge dtype detected inline by wave 0 (hi dwords of first 64 entries).
__global__ __launch_bounds__(256)
void coarse_bin(const void* __restrict__ ei, int* __restrict__ gcur,
                unsigned* __restrict__ segc, int E, int NCB) {
    __shared__ int cnt[1024];
    __shared__ int basel[1024];
    __shared__ int s_is64;
    const int tid = threadIdx.x;
    const long e0 = (long)blockIdx.x * EPB;
    const int ecnt = (int)min((long)EPB, (long)E - e0);

    if (tid < 64) {
        const int v = ((const int*)ei)[2 * tid + 1];
        const unsigned long long b = __ballot(v != 0);
        if (tid == 0) s_is64 = (b == 0ull);
    }
    for (int i = tid; i < NCB; i += 256) cnt[i] = 0;
    __syncthreads();
    const int is64 = s_is64;

    for (int j = tid; j < ecnt; j += 256) {
        int t = is64 ? (int)((const long long*)ei)[E + e0 + j]
                     : ((const int*)ei)[E + e0 + j];
        atomicAdd(&cnt[t >> CBITS], 1);
    }
    __syncthreads();

    for (int c = tid; c < NCB; c += 256) {
        const int n = cnt[c];
        const int na = (n + 15) & ~15;
        int b = 0;
        if (na > 0) b = atomicAdd(&gcur[c * 16], na);
        basel[c] = b;
        cnt[c] = 0;
        unsigned* sp = segc + (long)c * CCAP;
        for (int i = n; i < na; ++i)
            if (b + i < CCAP) sp[b + i] = 0xFFFFFFFFu;
    }
    __syncthreads();

    for (int j = tid; j < ecnt; j += 256) {
        int s, t;
        if (is64) { const long long* p = (const long long*)ei; s = (int)p[e0 + j]; t = (int)p[E + e0 + j]; }
        else      { const int* p = (const int*)ei;             s = p[e0 + j];      t = p[E + e0 + j]; }
        const int c = t >> CBITS;
        const int r = atomicAdd(&cnt[c], 1);
        const int pos = basel[c] + r;
        if (pos < CCAP)
            segc[(long)c * CCAP + pos] = ((unsigned)s << CBITS) | (unsigned)(t & (CSIZE - 1));
    }
}

// Stage 2+3 FUSED: per 128-node bucket (512 thr, 8 waves; 4 blocks/CU):
// histogram + scan + scatter build the node-ordered edge list IN LDS (order[]),
// then the gather phase consumes it in place -- no gorder/rowdeg round trip,
// no ordl restage, one fewer launch.
// Gather decomposition: wave = 4 node-slots x 16 lanes; each 16-lane group owns
// one node's full 128-B fp8 row (uint2/lane) and walks its edge slice
// sequentially with 2-way ILP. NO cross-lane reduction: each lane scales+packs
// its own 8 channels and stores one uint4 (16 lanes = full 256-B aggb row).
// order[] entries: with CBITS=7, e & ~127 == src*128 == byte offset into x8,
// so addressing is pure 32-bit. order[] reads are 16-lane broadcasts (free).
__global__ __launch_bounds__(512)
void refine_gather(const int* __restrict__ gcur, const unsigned* __restrict__ segc,
                   const unsigned char* __restrict__ x8,
                   unsigned short* __restrict__ aggb, int M) {
    __shared__ unsigned order[CCAP];            // 16 KB (src byte offsets)
    __shared__ int degh[CSIZE], scn[CSIZE], cur[CSIZE];
    const int tid = threadIdx.x;
    const int cb = blockIdx.x;
    const int nbase = cb << CBITS;
    const int nn = min(CSIZE, M - nbase);
    const int len = min(gcur[cb * 16], CCAP);
    const unsigned* sp = segc + (long)cb * CCAP;

    if (tid < CSIZE) degh[tid] = 0;
    __syncthreads();
    for (int i = tid; i < len; i += 512) {
        const unsigned e = sp[i];
        if (e != 0xFFFFFFFFu) atomicAdd(&degh[e & (CSIZE - 1)], 1);
    }
    __syncthreads();
    if (tid < CSIZE) scn[tid] = degh[tid];
    __syncthreads();
    for (int off = 1; off < CSIZE; off <<= 1) {
        int v = 0;
        if (tid >= off && tid < CSIZE) v = scn[tid - off];
        __syncthreads();
        if (tid < CSIZE) scn[tid] += v;
        __syncthreads();
    }
    if (tid < CSIZE) cur[tid] = scn[tid] - degh[tid];
    __syncthreads();
    for (int i = tid; i < len; i += 512) {
        const unsigned e = sp[i];
        if (e != 0xFFFFFFFFu) {
            const int r = atomicAdd(&cur[e & (CSIZE - 1)], 1);
            order[r] = e & ~(unsigned)(CSIZE - 1);   // src << 7 = byte offset into x8
        }
    }
    __syncthreads();

    // ---- gather phase ----
    const int lane = tid & 63;
    const int wave = tid >> 6;       // 0..7
    const int ns   = lane >> 4;      // node slot 0..3
    const int c2   = lane & 15;      // uint2 column: channels c2*8 .. c2*8+7
    const unsigned chb = (unsigned)c2 * 8;

    for (int base = wave * 4; base < nn; base += 32) {
        const int nl = base + ns;
        int deg = 0, beg = 0;
        if (nl < nn) { deg = degh[nl]; beg = scn[nl] - deg; }
        f32x2 a0 = {0.f, 0.f}, a1 = {0.f, 0.f}, a2 = {0.f, 0.f}, a3 = {0.f, 0.f};
        int i = 0;
        for (; i + 2 <= deg; i += 2) {
            const unsigned o0 = order[beg + i];
            const unsigned o1 = order[beg + i + 1];
            uint2 v0 = *(const uint2*)(x8 + (o0 + chb));
            uint2 v1 = *(const uint2*)(x8 + (o1 + chb));
            acc8(a0, a1, a2, a3, v0);
            acc8(a0, a1, a2, a3, v1);
        }
        if (i < deg) {
            const unsigned o0 = order[beg + i];
            uint2 v0 = *(const uint2*)(x8 + (o0 + chb));
            acc8(a0, a1, a2, a3, v0);
        }
        if (nl < nn) {
            const float rdiv = 1.0f / fmaxf((float)deg, 1.0f);
            unsigned w0 = (unsigned)f2bf(a0.x * rdiv) | ((unsigned)f2bf(a0.y * rdiv) << 16);
            unsigned w1 = (unsigned)f2bf(a1.x * rdiv) | ((unsigned)f2bf(a1.y * rdiv) << 16);
            unsigned w2 = (unsigned)f2bf(a2.x * rdiv) | ((unsigned)f2bf(a2.y * rdiv) << 16);
            unsigned w3 = (unsigned)f2bf(a3.x * rdiv) | ((unsigned)f2bf(a3.y * rdiv) << 16);
            *(uint4*)(aggb + (long)(nbase + nl) * 128 + c2 * 8) = make_uint4(w0, w1, w2, w3);
        }
    }
}

// GEMM v4: T3+T4 pipelined M-loop. 512 resident blocks (2/CU), each grid-strides
// over 32-row x 256-col tiles. A staged into a 4-deep LDS ring (4 x 16 KB) via
// async global_load_lds; counted s_waitcnt vmcnt(8) (never 0 in steady state) +
// ONE raw s_barrier per tile. B (128 KB, L2-hot) + bias hoisted into registers
// once per block, so the steady-state loop's ONLY vmem ops are the 4 staging
// g2lds per wave -> counted vmcnt is exact. Pool accumulates in registers across
// tiles; single atomic flush per block. Source chunks XOR-swizzled (cs = cl^rw)
// so the linear LDS dest reads back with the same involution on ds_read_b128.
__global__ __launch_bounds__(256, 2)
void gemm_pool(const unsigned short* __restrict__ xb, const unsigned short* __restrict__ aggb,
               const unsigned short* __restrict__ Bsw, const float* __restrict__ bias2,
               float* __restrict__ pooled_pad, int M, int NT) {
    __shared__ unsigned short As[4 * 32 * 256];   // 64 KB: 4 bufs x (32 rows x 512 B)
    const int tid  = threadIdx.x;
    const int lane = tid & 63;
    const int wn2  = tid >> 6;        // wave = 64-col group 0..3
    const int lrow = lane & 15;
    const int quad = lane >> 4;
    const int bid  = blockIdx.x;
    const int GRID = gridDim.x;
    const int nt   = (NT - bid + GRID - 1) / GRID;   // tiles for this block (uniform)
    if (nt <= 0) return;

    // ---- B frags (32 x uint4 = 128 VGPR) + bias, once per block (L2-hot) ----
    uint4 bb[8][4];
    #pragma unroll
    for (int kk = 0; kk < 8; ++kk)
        #pragma unroll
        for (int t = 0; t < 4; ++t)
            bb[kk][t] = *(const uint4*)&Bsw[((((long)kk * 4 + wn2) * 4 + t) * 64 + lane) * 8];
    float bv[4];
    #pragma unroll
    for (int t = 0; t < 4; ++t) bv[t] = bias2[wn2 * 64 + t * 16 + lrow];

    // staging constants: thread covers (row%8 = rw, LDS chunk cl), source chunk cl^rw
    const int cl = tid & 31;
    const int rw = tid >> 5;
    const int cs = cl ^ rw;
    const unsigned short* sbase = (cs < 16) ? (xb + (long)cs * 8)
                                            : (aggb + (long)(cs - 16) * 8);
    char* lbase = (char*)As + rw * 512 + cl * 16;

    auto STAGE = [&](int p) {
        const long trow = ((long)bid + (long)p * GRID) * 32;
        char* ld = lbase + (p & 3) * 16384;
        #pragma unroll
        for (int s = 0; s < 4; ++s)
            g2lds16(sbase + (trow + s * 8 + rw) * 128, ld + s * 4096);
    };

    #pragma unroll
    for (int p = 0; p < 3; ++p) if (p < nt) STAGE(p);

    float ps[4] = {0.f, 0.f, 0.f, 0.f};

    for (int p = 0; p < nt; ++p) {
        const int rem = nt - 1 - p;
        if (rem >= 2)      asm volatile("s_waitcnt vmcnt(8)" ::: "memory");
        else if (rem == 1) asm volatile("s_waitcnt vmcnt(4)" ::: "memory");
        else               asm volatile("s_waitcnt vmcnt(0)" ::: "memory");
        __builtin_amdgcn_s_barrier();
        if (p + 3 < nt) STAGE(p + 3);   // 12 wave-loads in flight during compute

        const char* Ab = (const char*)As + (p & 3) * 16384;
        f32x4 acc[2][4] = {};
        #pragma unroll
        for (int kk = 0; kk < 8; ++kk) {
            uint4 aC[2];
            #pragma unroll
            for (int i = 0; i < 2; ++i) {
                const int r = i * 16 + lrow;   // r&7 == lrow&7
                aC[i] = *(const uint4*)(Ab + r * 512 + (((kk * 4 + quad) ^ (lrow & 7)) * 16));
            }
            #pragma unroll
            for (int i = 0; i < 2; ++i)
                #pragma unroll
                for (int t = 0; t < 4; ++t)
                    acc[i][t] = __builtin_amdgcn_mfma_f32_16x16x32_bf16(
                        *(bf16x8*)&aC[i], *(bf16x8*)&bb[kk][t], acc[i][t], 0, 0, 0);
        }

        // bias + ReLU + masked row-sum, accumulated in registers across tiles
        const long trow = ((long)bid + (long)p * GRID) * 32;
        #pragma unroll
        for (int t = 0; t < 4; ++t) {
            float s = 0.f;
            #pragma unroll
            for (int i = 0; i < 2; ++i) {
                const long rbase = trow + i * 16 + quad * 4;
                #pragma unroll
                for (int r = 0; r < 4; ++r) {
                    float h = fmaxf(acc[i][t][r] + bv[t], 0.f);
                    if (rbase + r < M) s += h;
                }
            }
            ps[t] += s;
        }
    }

    // single pooled flush per block
    #pragma unroll
    for (int t = 0; t < 4; ++t) {
        ps[t] += __shfl_xor(ps[t], 16);
        ps[t] += __shfl_xor(ps[t], 32);
        if (quad == 0)
            atomicAdd(&pooled_pad[(wn2 * 64 + t * 16 + lrow) * 16], ps[t]);
    }
}

// pooled -> MLP head -> log_softmax. One block, 256 threads.
__global__ __launch_bounds__(256)
void head_kernel(const float* __restrict__ pooled_pad,
                 const float* __restrict__ W1, const float* __restrict__ b1,
                 const float* __restrict__ W2, const float* __restrict__ b2,
                 float* __restrict__ out, float invM) {
    __shared__ float pooled_s[256];
    __shared__ float z1_s[256];
    __shared__ float z2_s[10];
    const int j = threadIdx.x;

    pooled_s[j] = pooled_pad[j * 16] * invM;
    __syncthreads();

    const float4* w4 = (const float4*)(W1 + (long)j * 256);
    float sx = 0.f, sy = 0.f, sz = 0.f, sw = 0.f;
    #pragma unroll 8
    for (int k = 0; k < 64; ++k) {
        float4 w = w4[k];
        float4 p = *(const float4*)&pooled_s[k * 4];
        sx += w.x * p.x; sy += w.y * p.y; sz += w.z * p.z; sw += w.w * p.w;
    }
    z1_s[j] = fmaxf(b1[j] + sx + sy + sz + sw, 0.f);
    __syncthreads();

    if (j < 160) {
        const int c = j >> 4, q = j & 15;
        float s = 0.f;
        for (int k = q; k < 256; k += 16) s += W2[c * 256 + k] * z1_s[k];
        #pragma unroll
        for (int off = 8; off >= 1; off >>= 1) s += __shfl_down(s, off, 16);
        if (q == 0) z2_s[c] = s + b2[c];
    }
    __syncthreads();

    if (j == 0) {
        float mx = z2_s[0];
        for (int c = 1; c < 10; ++c) mx = fmaxf(mx, z2_s[c]);
        float se = 0.f;
        for (int c = 0; c < 10; ++c) se += expf(z2_s[c] - mx);
        const float ls = logf(se);
        for (int c = 0; c < 10; ++c) out[c] = z2_s[c] - mx - ls;
    }
}

extern "C" void kernel_launch(void* const* d_in, const int* in_sizes, int n_in,
                              void* d_out, int out_size, void* d_ws, size_t ws_size,
                              hipStream_t stream) {
    const float* x    = (const float*)d_in[0];
    const void*  ei   = d_in[1];
    const float* Wl   = (const float*)d_in[2];
    const float* Wr   = (const float*)d_in[3];
    const float* bias = (const float*)d_in[4];
    const float* W1   = (const float*)d_in[5];
    const float* b1   = (const float*)d_in[6];
    const float* W2   = (const float*)d_in[7];
    const float* b2   = (const float*)d_in[8];
    float* out = (float*)d_out;

    const int M = in_sizes[0] / D_IN;        // 100000 nodes
    const int E = in_sizes[1] / 2;           // 1.6M edges
    const int L = in_sizes[4] / D_HID;       // 3 layers
    const int NMB = (M + 127) / 128;         // 128-row pad granules
    const long Mpad = (long)NMB * 128;       // row-padded region size (GEMM OOB-safe)
    const int NCB = (M + CSIZE - 1) / CSIZE; // buckets (782)
    const int NB1 = (E + EPB - 1) / EPB;     // coarse_bin blocks (196)
    const int NT  = (M + 31) / 32;           // gemm 32-row tiles (3125)
    const int NG  = (NT < 512) ? NT : 512;   // resident grid: 2 blocks/CU

    // Only the LAST layer matters (h is overwritten each loop iteration).
    const float* Wl2   = Wl + (long)(L - 1) * D_HID * D_IN;
    const float* Wr2   = Wr + (long)(L - 1) * D_HID * D_IN;
    const float* bias2 = bias + (long)(L - 1) * D_HID;

    // workspace: xb[Mpad*128]bf16 | aggb[Mpad*128]bf16 | x8[Mpad*128]u8 | Bsw[256*256]bf16 |
    //            pooled_pad[256*16]f | gcur[NCB*16]i | segc[NCB*CCAP]u
    //            (pad rows of xb/aggb are garbage; GEMM masks rows >= M)
    unsigned short* xb   = (unsigned short*)d_ws;
    unsigned short* aggb = xb + Mpad * D_IN;
    unsigned char*  x8   = (unsigned char*)(aggb + Mpad * D_IN);
    unsigned short* Bsw  = (unsigned short*)(x8 + Mpad * D_IN);
    float* pooled_pad    = (float*)(Bsw + 256 * 256);
    int*      gcur       = (int*)(pooled_pad + 256 * 16);
    unsigned* segc       = (unsigned*)(gcur + (long)NCB * 16);

    const long n16 = (long)M * 8;            // 16-float chunks of x
    const int NXB = (int)((n16 + 255) / 256);

    prep<<<NXB + 32 + 1, 256, 0, stream>>>(x, xb, x8, Wr2, Wl2, Bsw, gcur, pooled_pad,
                                           n16, NXB, NCB);
    coarse_bin<<<NB1, 256, 0, stream>>>(ei, gcur, segc, E, NCB);
    refine_gather<<<NCB, 512, 0, stream>>>(gcur, segc, x8, aggb, M);

    gemm_pool<<<NG, 256, 0, stream>>>(xb, aggb, Bsw, bias2, pooled_pad, M, NT);

    head_kernel<<<1, 256, 0, stream>>>(pooled_pad, W1, b1, W2, b2, out, 1.0f / (float)M);
}

// Round 5
// 214.280 us; speedup vs baseline: 1.2970x; 1.0978x over previous
//
#include <hip/hip_runtime.h>
#include <hip/hip_bf16.h>

#define D_IN  128
#define D_HID 256
#define CBITS 7
#define CSIZE 128          // nodes per bucket (one refine_gather block)
#define EPB   4096         // edges per coarse_bin block
#define CCAP  4096         // entry capacity per bucket (mean 2048, +many sigma; no pad now)

typedef __bf16 bf16x8 __attribute__((ext_vector_type(8)));
typedef float  f32x4  __attribute__((ext_vector_type(4)));
typedef float  f32x2  __attribute__((ext_vector_type(2)));

__device__ __forceinline__ unsigned short f2bf(float f) {
    unsigned u = __float_as_uint(f);
    u += 0x7FFFu + ((u >> 16) & 1u);   // RNE
    return (unsigned short)(u >> 16);
}
__device__ __forceinline__ uint2 pack4(float4 v) {
    unsigned lo = (unsigned)f2bf(v.x) | ((unsigned)f2bf(v.y) << 16);
    unsigned hi = (unsigned)f2bf(v.z) | ((unsigned)f2bf(v.w) << 16);
    return make_uint2(lo, hi);
}
// pack 4 floats -> 4 fp8 e4m3 bytes (HW cvt)
__device__ __forceinline__ unsigned packfp8(float4 v) {
    int u = __builtin_amdgcn_cvt_pk_fp8_f32(v.x, v.y, 0, false);
    u = __builtin_amdgcn_cvt_pk_fp8_f32(v.z, v.w, u, true);
    return (unsigned)u;
}
// async 16B global -> LDS (vmcnt)
__device__ __forceinline__ void g2lds16(const void* g, void* l) {
    __builtin_amdgcn_global_load_lds(
        (const __attribute__((address_space(1))) unsigned int*)g,
        (__attribute__((address_space(3))) unsigned int*)l, 16, 0, 0);
}
// accumulate 8 fp8 channels (one uint2) into 4 packed f32x2 accumulators
__device__ __forceinline__ void acc8(f32x2& a0, f32x2& a1, f32x2& a2, f32x2& a3, uint2 v) {
    a0 += __builtin_amdgcn_cvt_pk_f32_fp8(v.x, false);
    a1 += __builtin_amdgcn_cvt_pk_f32_fp8(v.x, true);
    a2 += __builtin_amdgcn_cvt_pk_f32_fp8(v.y, false);
    a3 += __builtin_amdgcn_cvt_pk_f32_fp8(v.y, true);
}

// Fused prep: [0,NXB) convert x -> bf16+fp8; [NXB,NXB+32) pack B into MFMA-fragment
// order; last block zeros gcur + pooled_pad. One launch instead of four.
__global__ __launch_bounds__(256)
void prep(const float* __restrict__ x, unsigned short* __restrict__ xb,
          unsigned char* __restrict__ x8,
          const float* __restrict__ Wr2, const float* __restrict__ Wl2,
          unsigned short* __restrict__ Bsw,
          int* __restrict__ gcur, float* __restrict__ pooled_pad,
          long n16, int NXB, int NCB) {
    const int bid = blockIdx.x;
    const int tid = threadIdx.x;
    if (bid < NXB) {
        const long t = (long)bid * 256 + tid;
        if (t >= n16) return;
        const float4* x4 = (const float4*)x;
        float4 v0 = x4[t * 4], v1 = x4[t * 4 + 1], v2 = x4[t * 4 + 2], v3 = x4[t * 4 + 3];
        uint2 p0 = pack4(v0), p1 = pack4(v1), p2 = pack4(v2), p3 = pack4(v3);
        ((uint4*)xb)[t * 2]     = make_uint4(p0.x, p0.y, p1.x, p1.y);
        ((uint4*)xb)[t * 2 + 1] = make_uint4(p2.x, p2.y, p3.x, p3.y);
        ((uint4*)x8)[t] = make_uint4(packfp8(v0), packfp8(v1), packfp8(v2), packfp8(v3));
    } else if (bid < NXB + 32) {
        // Bsw[(((kk*4+wn2)*4+t)*64+lane)*8+e] = B[wn2*64+t*16+(lane&15)][kk*32+(lane>>4)*8+e]
        const int t_idx = (bid - NXB) * 256 + tid;
        const int lane = t_idx & 63;
        const int rest = t_idx >> 6;
        const int tt   = rest & 3;
        const int wn2  = (rest >> 2) & 3;
        const int kk   = rest >> 4;
        const int j = wn2 * 64 + tt * 16 + (lane & 15);
        const int k = kk * 32 + (lane >> 4) * 8;
        const float* src = (k < 128) ? &Wr2[j * 128 + k] : &Wl2[j * 128 + (k - 128)];
        float4 v0 = *(const float4*)src;
        float4 v1 = *(const float4*)(src + 4);
        uint2 p0 = pack4(v0), p1 = pack4(v1);
        *(uint4*)&Bsw[(long)t_idx * 8] = make_uint4(p0.x, p0.y, p1.x, p1.y);
    } else {
        for (int i = tid; i < NCB * 16; i += 256) gcur[i] = 0;
        for (int i = tid; i < 256 * 16; i += 256) pooled_pad[i] = 0.f;
    }
}

// Stage 1 v2: block-local counting sort. Each thread holds its 8 edges in
// REGISTERS (one global read pass); LDS histogram + 1024-wide scan + LDS
// scatter produce the block's edge list sorted by bucket; write-out is
// thread-per-entry over the sorted array so consecutive threads write
// consecutive addresses within each bucket run (coalesced in space AND time).
// No 16-slot padding -> gcur holds exact counts, no pad writes.
// int64-vs-int32 edge dtype detected inline by wave 0.
__global__ __launch_bounds__(512)
void coarse_bin(const void* __restrict__ ei, int* __restrict__ gcur,
                unsigned* __restrict__ segc, int E, int NCB) {
    __shared__ unsigned sorted[EPB];          // 16 KB
    __shared__ unsigned short bkt[EPB];       // 8 KB
    __shared__ int cnt[1024], scn[1024], cur[1024], gbase[1024];  // 16 KB
    __shared__ int s_is64;
    const int tid = threadIdx.x;
    const long e0 = (long)blockIdx.x * EPB;
    const int ecnt = (int)min((long)EPB, (long)E - e0);

    if (tid < 64) {
        const int v = ((const int*)ei)[2 * tid + 1];
        const unsigned long long b = __ballot(v != 0);
        if (tid == 0) s_is64 = (b == 0ull);
    }
    for (int i = tid; i < 1024; i += 512) cnt[i] = 0;
    __syncthreads();
    const int is64 = s_is64;

    // load edges into registers + histogram
    int sv[8], tv[8];
    #pragma unroll
    for (int k = 0; k < 8; ++k) {
        const int j = tid + k * 512;
        if (j < ecnt) {
            if (is64) {
                sv[k] = (int)((const long long*)ei)[e0 + j];
                tv[k] = (int)((const long long*)ei)[E + e0 + j];
            } else {
                sv[k] = ((const int*)ei)[e0 + j];
                tv[k] = ((const int*)ei)[E + e0 + j];
            }
            atomicAdd(&cnt[tv[k] >> CBITS], 1);
        }
    }
    __syncthreads();

    // inclusive scan over 1024 (2 elems/thread, Hillis-Steele)
    scn[tid] = cnt[tid];
    scn[tid + 512] = cnt[tid + 512];
    __syncthreads();
    for (int off = 1; off < 1024; off <<= 1) {
        const int v0 = (tid >= off) ? scn[tid - off] : 0;
        const int v1 = (tid + 512 >= off) ? scn[tid + 512 - off] : 0;
        __syncthreads();
        scn[tid] += v0;
        scn[tid + 512] += v1;
        __syncthreads();
    }
    cur[tid] = scn[tid] - cnt[tid];
    cur[tid + 512] = scn[tid + 512] - cnt[tid + 512];
    // global segment base per bucket (exact counts, no padding)
    for (int c = tid; c < NCB; c += 512)
        gbase[c] = cnt[c] ? atomicAdd(&gcur[c * 16], cnt[c]) : 0;
    __syncthreads();

    // scatter into LDS sorted order
    #pragma unroll
    for (int k = 0; k < 8; ++k) {
        const int j = tid + k * 512;
        if (j < ecnt) {
            const int c = tv[k] >> CBITS;
            const int r = atomicAdd(&cur[c], 1);
            sorted[r] = ((unsigned)sv[k] << CBITS) | (unsigned)(tv[k] & (CSIZE - 1));
            bkt[r] = (unsigned short)c;
        }
    }
    __syncthreads();

    // streamed, run-coalesced write-out
    for (int i = tid; i < ecnt; i += 512) {
        const int c = bkt[i];
        const int pos = gbase[c] + (i - (scn[c] - cnt[c]));
        if (pos < CCAP) segc[(long)c * CCAP + pos] = sorted[i];
    }
}

// Stage 2+3 FUSED: per 128-node bucket (512 thr, 8 waves; 4 blocks/CU):
// histogram + scan + scatter build the node-ordered edge list IN LDS (order[]),
// then the gather phase consumes it in place -- no gorder/rowdeg round trip,
// no ordl restage, one fewer launch.
// Gather decomposition: wave = 4 node-slots x 16 lanes; each 16-lane group owns
// one node's full 128-B fp8 row (uint2/lane) and walks its edge slice
// sequentially with 2-way ILP. NO cross-lane reduction: each lane scales+packs
// its own 8 channels and stores one uint4 (16 lanes = full 256-B aggb row).
// order[] entries: with CBITS=7, e & ~127 == src*128 == byte offset into x8,
// so addressing is pure 32-bit. order[] reads are 16-lane broadcasts (free).
__global__ __launch_bounds__(512)
void refine_gather(const int* __restrict__ gcur, const unsigned* __restrict__ segc,
                   const unsigned char* __restrict__ x8,
                   unsigned short* __restrict__ aggb, int M) {
    __shared__ unsigned order[CCAP];            // 16 KB (src byte offsets)
    __shared__ int degh[CSIZE], scn[CSIZE], cur[CSIZE];
    const int tid = threadIdx.x;
    const int cb = blockIdx.x;
    const int nbase = cb << CBITS;
    const int nn = min(CSIZE, M - nbase);
    const int len = min(gcur[cb * 16], CCAP);
    const unsigned* sp = segc + (long)cb * CCAP;

    if (tid < CSIZE) degh[tid] = 0;
    __syncthreads();
    for (int i = tid; i < len; i += 512) {
        const unsigned e = sp[i];
        if (e != 0xFFFFFFFFu) atomicAdd(&degh[e & (CSIZE - 1)], 1);
    }
    __syncthreads();
    if (tid < CSIZE) scn[tid] = degh[tid];
    __syncthreads();
    for (int off = 1; off < CSIZE; off <<= 1) {
        int v = 0;
        if (tid >= off && tid < CSIZE) v = scn[tid - off];
        __syncthreads();
        if (tid < CSIZE) scn[tid] += v;
        __syncthreads();
    }
    if (tid < CSIZE) cur[tid] = scn[tid] - degh[tid];
    __syncthreads();
    for (int i = tid; i < len; i += 512) {
        const unsigned e = sp[i];
        if (e != 0xFFFFFFFFu) {
            const int r = atomicAdd(&cur[e & (CSIZE - 1)], 1);
            order[r] = e & ~(unsigned)(CSIZE - 1);   // src << 7 = byte offset into x8
        }
    }
    __syncthreads();

    // ---- gather phase ----
    const int lane = tid & 63;
    const int wave = tid >> 6;       // 0..7
    const int ns   = lane >> 4;      // node slot 0..3
    const int c2   = lane & 15;      // uint2 column: channels c2*8 .. c2*8+7
    const unsigned chb = (unsigned)c2 * 8;

    for (int base = wave * 4; base < nn; base += 32) {
        const int nl = base + ns;
        int deg = 0, beg = 0;
        if (nl < nn) { deg = degh[nl]; beg = scn[nl] - deg; }
        f32x2 a0 = {0.f, 0.f}, a1 = {0.f, 0.f}, a2 = {0.f, 0.f}, a3 = {0.f, 0.f};
        int i = 0;
        for (; i + 2 <= deg; i += 2) {
            const unsigned o0 = order[beg + i];
            const unsigned o1 = order[beg + i + 1];
            uint2 v0 = *(const uint2*)(x8 + (o0 + chb));
            uint2 v1 = *(const uint2*)(x8 + (o1 + chb));
            acc8(a0, a1, a2, a3, v0);
            acc8(a0, a1, a2, a3, v1);
        }
        if (i < deg) {
            const unsigned o0 = order[beg + i];
            uint2 v0 = *(const uint2*)(x8 + (o0 + chb));
            acc8(a0, a1, a2, a3, v0);
        }
        if (nl < nn) {
            const float rdiv = 1.0f / fmaxf((float)deg, 1.0f);
            unsigned w0 = (unsigned)f2bf(a0.x * rdiv) | ((unsigned)f2bf(a0.y * rdiv) << 16);
            unsigned w1 = (unsigned)f2bf(a1.x * rdiv) | ((unsigned)f2bf(a1.y * rdiv) << 16);
            unsigned w2 = (unsigned)f2bf(a2.x * rdiv) | ((unsigned)f2bf(a2.y * rdiv) << 16);
            unsigned w3 = (unsigned)f2bf(a3.x * rdiv) | ((unsigned)f2bf(a3.y * rdiv) << 16);
            *(uint4*)(aggb + (long)(nbase + nl) * 128 + c2 * 8) = make_uint4(w0, w1, w2, w3);
        }
    }
}

// GEMM v4: T3+T4 pipelined M-loop. 512 resident blocks (2/CU), each grid-strides
// over 32-row x 256-col tiles. A staged into a 4-deep LDS ring (4 x 16 KB) via
// async global_load_lds; counted s_waitcnt vmcnt(8) (never 0 in steady state) +
// ONE raw s_barrier per tile. B (128 KB, L2-hot) + bias hoisted into registers
// once per block, so the steady-state loop's ONLY vmem ops are the 4 staging
// g2lds per wave -> counted vmcnt is exact. Pool accumulates in registers across
// tiles; single atomic flush per block. Source chunks XOR-swizzled (cs = cl^rw)
// so the linear LDS dest reads back with the same involution on ds_read_b128.
__global__ __launch_bounds__(256, 2)
void gemm_pool(const unsigned short* __restrict__ xb, const unsigned short* __restrict__ aggb,
               const unsigned short* __restrict__ Bsw, const float* __restrict__ bias2,
               float* __restrict__ pooled_pad, int M, int NT) {
    __shared__ unsigned short As[4 * 32 * 256];   // 64 KB: 4 bufs x (32 rows x 512 B)
    const int tid  = threadIdx.x;
    const int lane = tid & 63;
    const int wn2  = tid >> 6;        // wave = 64-col group 0..3
    const int lrow = lane & 15;
    const int quad = lane >> 4;
    const int bid  = blockIdx.x;
    const int GRID = gridDim.x;
    const int nt   = (NT - bid + GRID - 1) / GRID;   // tiles for this block (uniform)
    if (nt <= 0) return;

    // ---- B frags (32 x uint4 = 128 VGPR) + bias, once per block (L2-hot) ----
    uint4 bb[8][4];
    #pragma unroll
    for (int kk = 0; kk < 8; ++kk)
        #pragma unroll
        for (int t = 0; t < 4; ++t)
            bb[kk][t] = *(const uint4*)&Bsw[((((long)kk * 4 + wn2) * 4 + t) * 64 + lane) * 8];
    float bv[4];
    #pragma unroll
    for (int t = 0; t < 4; ++t) bv[t] = bias2[wn2 * 64 + t * 16 + lrow];

    // staging constants: thread covers (row%8 = rw, LDS chunk cl), source chunk cl^rw
    const int cl = tid & 31;
    const int rw = tid >> 5;
    const int cs = cl ^ rw;
    const unsigned short* sbase = (cs < 16) ? (xb + (long)cs * 8)
                                            : (aggb + (long)(cs - 16) * 8);
    char* lbase = (char*)As + rw * 512 + cl * 16;

    auto STAGE = [&](int p) {
        const long trow = ((long)bid + (long)p * GRID) * 32;
        char* ld = lbase + (p & 3) * 16384;
        #pragma unroll
        for (int s = 0; s < 4; ++s)
            g2lds16(sbase + (trow + s * 8 + rw) * 128, ld + s * 4096);
    };

    #pragma unroll
    for (int p = 0; p < 3; ++p) if (p < nt) STAGE(p);

    float ps[4] = {0.f, 0.f, 0.f, 0.f};

    for (int p = 0; p < nt; ++p) {
        const int rem = nt - 1 - p;
        if (rem >= 2)      asm volatile("s_waitcnt vmcnt(8)" ::: "memory");
        else if (rem == 1) asm volatile("s_waitcnt vmcnt(4)" ::: "memory");
        else               asm volatile("s_waitcnt vmcnt(0)" ::: "memory");
        __builtin_amdgcn_s_barrier();
        if (p + 3 < nt) STAGE(p + 3);   // 12 wave-loads in flight during compute

        const char* Ab = (const char*)As + (p & 3) * 16384;
        f32x4 acc[2][4] = {};
        #pragma unroll
        for (int kk = 0; kk < 8; ++kk) {
            uint4 aC[2];
            #pragma unroll
            for (int i = 0; i < 2; ++i) {
                const int r = i * 16 + lrow;   // r&7 == lrow&7
                aC[i] = *(const uint4*)(Ab + r * 512 + (((kk * 4 + quad) ^ (lrow & 7)) * 16));
            }
            #pragma unroll
            for (int i = 0; i < 2; ++i)
                #pragma unroll
                for (int t = 0; t < 4; ++t)
                    acc[i][t] = __builtin_amdgcn_mfma_f32_16x16x32_bf16(
                        *(bf16x8*)&aC[i], *(bf16x8*)&bb[kk][t], acc[i][t], 0, 0, 0);
        }

        // bias + ReLU + masked row-sum, accumulated in registers across tiles
        const long trow = ((long)bid + (long)p * GRID) * 32;
        #pragma unroll
        for (int t = 0; t < 4; ++t) {
            float s = 0.f;
            #pragma unroll
            for (int i = 0; i < 2; ++i) {
                const long rbase = trow + i * 16 + quad * 4;
                #pragma unroll
                for (int r = 0; r < 4; ++r) {
                    float h = fmaxf(acc[i][t][r] + bv[t], 0.f);
                    if (rbase + r < M) s += h;
                }
            }
            ps[t] += s;
        }
    }

    // single pooled flush per block
    #pragma unroll
    for (int t = 0; t < 4; ++t) {
        ps[t] += __shfl_xor(ps[t], 16);
        ps[t] += __shfl_xor(ps[t], 32);
        if (quad == 0)
            atomicAdd(&pooled_pad[(wn2 * 64 + t * 16 + lrow) * 16], ps[t]);
    }
}

// pooled -> MLP head -> log_softmax. One block, 256 threads.
__global__ __launch_bounds__(256)
void head_kernel(const float* __restrict__ pooled_pad,
                 const float* __restrict__ W1, const float* __restrict__ b1,
                 const float* __restrict__ W2, const float* __restrict__ b2,
                 float* __restrict__ out, float invM) {
    __shared__ float pooled_s[256];
    __shared__ float z1_s[256];
    __shared__ float z2_s[10];
    const int j = threadIdx.x;

    pooled_s[j] = pooled_pad[j * 16] * invM;
    __syncthreads();

    const float4* w4 = (const float4*)(W1 + (long)j * 256);
    float sx = 0.f, sy = 0.f, sz = 0.f, sw = 0.f;
    #pragma unroll 8
    for (int k = 0; k < 64; ++k) {
        float4 w = w4[k];
        float4 p = *(const float4*)&pooled_s[k * 4];
        sx += w.x * p.x; sy += w.y * p.y; sz += w.z * p.z; sw += w.w * p.w;
    }
    z1_s[j] = fmaxf(b1[j] + sx + sy + sz + sw, 0.f);
    __syncthreads();

    if (j < 160) {
        const int c = j >> 4, q = j & 15;
        float s = 0.f;
        for (int k = q; k < 256; k += 16) s += W2[c * 256 + k] * z1_s[k];
        #pragma unroll
        for (int off = 8; off >= 1; off >>= 1) s += __shfl_down(s, off, 16);
        if (q == 0) z2_s[c] = s + b2[c];
    }
    __syncthreads();

    if (j == 0) {
        float mx = z2_s[0];
        for (int c = 1; c < 10; ++c) mx = fmaxf(mx, z2_s[c]);
        float se = 0.f;
        for (int c = 0; c < 10; ++c) se += expf(z2_s[c] - mx);
        const float ls = logf(se);
        for (int c = 0; c < 10; ++c) out[c] = z2_s[c] - mx - ls;
    }
}

extern "C" void kernel_launch(void* const* d_in, const int* in_sizes, int n_in,
                              void* d_out, int out_size, void* d_ws, size_t ws_size,
                              hipStream_t stream) {
    const float* x    = (const float*)d_in[0];
    const void*  ei   = d_in[1];
    const float* Wl   = (const float*)d_in[2];
    const float* Wr   = (const float*)d_in[3];
    const float* bias = (const float*)d_in[4];
    const float* W1   = (const float*)d_in[5];
    const float* b1   = (const float*)d_in[6];
    const float* W2   = (const float*)d_in[7];
    const float* b2   = (const float*)d_in[8];
    float* out = (float*)d_out;

    const int M = in_sizes[0] / D_IN;        // 100000 nodes
    const int E = in_sizes[1] / 2;           // 1.6M edges
    const int L = in_sizes[4] / D_HID;       // 3 layers
    const int NMB = (M + 127) / 128;         // 128-row pad granules
    const long Mpad = (long)NMB * 128;       // row-padded region size (GEMM OOB-safe)
    const int NCB = (M + CSIZE - 1) / CSIZE; // buckets (782)
    const int NB1 = (E + EPB - 1) / EPB;     // coarse_bin blocks (391)
    const int NT  = (M + 31) / 32;           // gemm 32-row tiles (3125)
    const int NG  = (NT < 512) ? NT : 512;   // resident grid: 2 blocks/CU

    // Only the LAST layer matters (h is overwritten each loop iteration).
    const float* Wl2   = Wl + (long)(L - 1) * D_HID * D_IN;
    const float* Wr2   = Wr + (long)(L - 1) * D_HID * D_IN;
    const float* bias2 = bias + (long)(L - 1) * D_HID;

    // workspace: xb[Mpad*128]bf16 | aggb[Mpad*128]bf16 | x8[Mpad*128]u8 | Bsw[256*256]bf16 |
    //            pooled_pad[256*16]f | gcur[NCB*16]i | segc[NCB*CCAP]u
    //            (pad rows of xb/aggb are garbage; GEMM masks rows >= M)
    unsigned short* xb   = (unsigned short*)d_ws;
    unsigned short* aggb = xb + Mpad * D_IN;
    unsigned char*  x8   = (unsigned char*)(aggb + Mpad * D_IN);
    unsigned short* Bsw  = (unsigned short*)(x8 + Mpad * D_IN);
    float* pooled_pad    = (float*)(Bsw + 256 * 256);
    int*      gcur       = (int*)(pooled_pad + 256 * 16);
    unsigned* segc       = (unsigned*)(gcur + (long)NCB * 16);

    const long n16 = (long)M * 8;            // 16-float chunks of x
    const int NXB = (int)((n16 + 255) / 256);

    prep<<<NXB + 32 + 1, 256, 0, stream>>>(x, xb, x8, Wr2, Wl2, Bsw, gcur, pooled_pad,
                                           n16, NXB, NCB);
    coarse_bin<<<NB1, 512, 0, stream>>>(ei, gcur, segc, E, NCB);
    refine_gather<<<NCB, 512, 0, stream>>>(gcur, segc, x8, aggb, M);

    gemm_pool<<<NG, 256, 0, stream>>>(xb, aggb, Bsw, bias2, pooled_pad, M, NT);

    head_kernel<<<1, 256, 0, stream>>>(pooled_pad, W1, b1, W2, b2, out, 1.0f / (float)M);
}